// Round 1
// baseline (2930.120 us; speedup 1.0000x reference)
//
#include <hip/hip_runtime.h>
#include <hip/hip_bf16.h>
#include <cstddef>

// ---------------------------------------------------------------------------
// LSTMSeq2Seq: B=4096, L=64, T=48, H=64, NH=4, HD=16, NQ=3
// All fp32 (accuracy threshold 3.125e-4 abs). Round 0: correctness-first.
// ---------------------------------------------------------------------------

#define B_   4096
#define L_   64
#define T_   48
#define H_   64
#define G_   256     // 4*H
#define ROWS 16      // batch rows per LSTM block

__device__ __forceinline__ float sigf(float x) { return 1.0f / (1.0f + expf(-x)); }

// ---------------------------------------------------------------------------
// Weight transposes (one-time): WTg[k][c] = concat(Wih,Whh)^T  (128 x 256)
// ---------------------------------------------------------------------------
__global__ void transpose_w_kernel(const float* __restrict__ Wih,
                                   const float* __restrict__ Whh,
                                   float* __restrict__ out) {
    int idx = blockIdx.x * 256 + threadIdx.x;      // [0, 16384)
    if (idx < 16384) {
        int r = idx >> 6, k = idx & 63;            // r: gate row (256), k: input chan
        out[k * 256 + r]        = Wih[idx];
        out[(64 + k) * 256 + r] = Whh[idx];
    }
}

// wqkvT[k][r] (64x192), woT[k][r] (64x64), w1T[k][r] (64x32)
__global__ void transpose_aux_kernel(const float* __restrict__ Wqkv,
                                     const float* __restrict__ Wo,
                                     const float* __restrict__ W1,
                                     float* __restrict__ wqkvT,
                                     float* __restrict__ woT,
                                     float* __restrict__ w1T) {
    int idx = blockIdx.x * 256 + threadIdx.x;
    if (idx < 12288) {
        int r = idx >> 6, k = idx & 63;
        wqkvT[k * 192 + r] = Wqkv[idx];
    } else if (idx < 16384) {
        int i = idx - 12288; int r = i >> 6, k = i & 63;
        woT[k * 64 + r] = Wo[i];
    } else if (idx < 18432) {
        int i = idx - 16384; int r = i >> 6, k = i & 63;
        w1T[k * 32 + r] = W1[i];
    }
}

// ---------------------------------------------------------------------------
// One LSTM layer over a full sequence. Each block owns ROWS batch rows.
// Dynamic LDS: WT[128][256] | A[16][132] | gb[16][260] | bs[256]
// mode 0: input = inseq[b][t][:]   (stride S*64)
// mode 1: input = (t==0) ? in0[b][:] : inseq[b][t-1][:]   (decoder L1)
// ---------------------------------------------------------------------------
__global__ __launch_bounds__(256) void lstm_layer_kernel(
    const float* __restrict__ inseq,
    const float* __restrict__ in0,
    const float* __restrict__ WTg,     // [128][256] pre-transposed
    const float* __restrict__ bih,
    const float* __restrict__ bhh,
    const float* __restrict__ h0,      // nullable -> zeros
    const float* __restrict__ c0,
    float* __restrict__ outseq,        // [B][S][64]
    float* __restrict__ hfin,          // nullable
    float* __restrict__ cfin,
    int S, int mode)
{
    extern __shared__ float lds[];
    float* WT   = lds;                       // 32768
    float* Abuf = lds + 32768;               // 16*132 = 2112
    float* gb   = lds + 32768 + 2112;        // 16*260 = 4160
    float* bs   = lds + 32768 + 2112 + 4160; // 256

    const int tid  = threadIdx.x;
    const int row0 = blockIdx.x * ROWS;

    // resident transposed weights (coalesced copy, L2-hot)
    for (int f = tid; f < 8192; f += 256)
        ((float4*)WT)[f] = ((const float4*)WTg)[f];
    bs[tid] = bih[tid] + bhh[tid];

    // staging map (input / h rows), cell-update map
    const int rs = tid >> 4, qs = tid & 15;
    const int rc = tid & 15, qc = tid >> 4;
    // GEMM map: wave covers 16 rows x 64 cols
    const int wv  = tid >> 6;
    const int cg  = tid & 15;
    const int rg  = (tid >> 4) & 3;
    const int cc0 = wv * 64 + cg * 4;
    const int rr0 = rg * 4;

    // prologue: stage t=0 input + h0, init c
    {
        const float* p0 = (mode == 1) ? (in0 + (size_t)(row0 + rs) * 64)
                                      : (inseq + (size_t)(row0 + rs) * S * 64);
        *(float4*)&Abuf[rs * 132 + qs * 4] = *(const float4*)(p0 + qs * 4);
        float4 h4 = make_float4(0.f, 0.f, 0.f, 0.f);
        if (h0) h4 = *(const float4*)(h0 + (size_t)(row0 + rs) * 64 + qs * 4);
        *(float4*)&Abuf[rs * 132 + 64 + qs * 4] = h4;
    }
    float cr0 = 0.f, cr1 = 0.f, cr2 = 0.f, cr3 = 0.f;
    if (c0) {
        float4 c4 = *(const float4*)(c0 + (size_t)(row0 + rc) * 64 + qc * 4);
        cr0 = c4.x; cr1 = c4.y; cr2 = c4.z; cr3 = c4.w;
    }
    float4 hlast = make_float4(0.f, 0.f, 0.f, 0.f);

    for (int t = 0; t < S; ++t) {
        // prefetch next input (global latency hidden under GEMM)
        float4 nxt = make_float4(0.f, 0.f, 0.f, 0.f);
        if (t + 1 < S) {
            const float* pn = (mode == 1)
                ? (inseq + ((size_t)(row0 + rs) * S + t) * 64)        // target[t]
                : (inseq + ((size_t)(row0 + rs) * S + (t + 1)) * 64);
            nxt = *(const float4*)(pn + qs * 4);
        }
        __syncthreads();   // A (and WT on first iter) ready

        // gates = [x_t | h] @ WT + bias   (16 x 256, K=128)
        float4 bj = *(const float4*)&bs[cc0];
        float acc[4][4];
        #pragma unroll
        for (int i = 0; i < 4; ++i) {
            acc[i][0] = bj.x; acc[i][1] = bj.y; acc[i][2] = bj.z; acc[i][3] = bj.w;
        }
        #pragma unroll 4
        for (int kk = 0; kk < 128; kk += 4) {
            float4 w0 = *(const float4*)&WT[(kk + 0) * 256 + cc0];
            float4 w1 = *(const float4*)&WT[(kk + 1) * 256 + cc0];
            float4 w2 = *(const float4*)&WT[(kk + 2) * 256 + cc0];
            float4 w3 = *(const float4*)&WT[(kk + 3) * 256 + cc0];
            #pragma unroll
            for (int i = 0; i < 4; ++i) {
                float4 a = *(const float4*)&Abuf[(rr0 + i) * 132 + kk];
                acc[i][0] += a.x * w0.x + a.y * w1.x + a.z * w2.x + a.w * w3.x;
                acc[i][1] += a.x * w0.y + a.y * w1.y + a.z * w2.y + a.w * w3.y;
                acc[i][2] += a.x * w0.z + a.y * w1.z + a.z * w2.z + a.w * w3.z;
                acc[i][3] += a.x * w0.w + a.y * w1.w + a.z * w2.w + a.w * w3.w;
            }
        }
        #pragma unroll
        for (int i = 0; i < 4; ++i)
            *(float4*)&gb[(rr0 + i) * 260 + cc0] =
                make_float4(acc[i][0], acc[i][1], acc[i][2], acc[i][3]);
        __syncthreads();   // gb ready; all A reads done

        if (t + 1 < S) *(float4*)&Abuf[rs * 132 + qs * 4] = nxt;

        // cell update: gate order i,f,g,o
        {
            float4 gi = *(const float4*)&gb[rc * 260 +   0 + qc * 4];
            float4 gf = *(const float4*)&gb[rc * 260 +  64 + qc * 4];
            float4 gg = *(const float4*)&gb[rc * 260 + 128 + qc * 4];
            float4 go = *(const float4*)&gb[rc * 260 + 192 + qc * 4];
            float4 hv;
            cr0 = sigf(gf.x) * cr0 + sigf(gi.x) * tanhf(gg.x); hv.x = sigf(go.x) * tanhf(cr0);
            cr1 = sigf(gf.y) * cr1 + sigf(gi.y) * tanhf(gg.y); hv.y = sigf(go.y) * tanhf(cr1);
            cr2 = sigf(gf.z) * cr2 + sigf(gi.z) * tanhf(gg.z); hv.z = sigf(go.z) * tanhf(cr2);
            cr3 = sigf(gf.w) * cr3 + sigf(gi.w) * tanhf(gg.w); hv.w = sigf(go.w) * tanhf(cr3);
            *(float4*)&Abuf[rc * 132 + 64 + qc * 4] = hv;
            *(float4*)&outseq[((size_t)(row0 + rc) * S + t) * 64 + qc * 4] = hv;
            hlast = hv;
        }
    }
    if (hfin) {
        *(float4*)&hfin[(size_t)(row0 + rc) * 64 + qc * 4] = hlast;
        *(float4*)&cfin[(size_t)(row0 + rc) * 64 + qc * 4] = make_float4(cr0, cr1, cr2, cr3);
    }
}

// ---------------------------------------------------------------------------
// Self-attention, but ONLY the last query position (that's all dec_in needs).
// One block per batch element.
// ---------------------------------------------------------------------------
__global__ __launch_bounds__(256) void attn0_kernel(
    const float* __restrict__ encout,
    const float* __restrict__ wqkvT,   // [64][192]
    const float* __restrict__ bqkv,
    const float* __restrict__ woT,     // [64][64]
    const float* __restrict__ bo,
    float* __restrict__ a0last)        // [B][64]
{
    __shared__ float E[64 * 65];
    __shared__ float Km[64 * 65];
    __shared__ float Vm[64 * 65];
    __shared__ float qv[64];
    __shared__ float wsm[4 * 64];
    __shared__ float ov[64];
    const int b = blockIdx.x, tid = threadIdx.x;

    for (int f = tid; f < 4096; f += 256)
        E[(f >> 6) * 65 + (f & 63)] = encout[(size_t)b * 4096 + f];
    __syncthreads();
    {
        const int j = tid & 63, sg = tid >> 6;
        float accK[16], accV[16];
        const float bk = bqkv[64 + j], bv = bqkv[128 + j];
        #pragma unroll
        for (int i = 0; i < 16; ++i) { accK[i] = bk; accV[i] = bv; }
        for (int k = 0; k < 64; ++k) {
            const float wk = wqkvT[k * 192 + 64 + j];
            const float wv = wqkvT[k * 192 + 128 + j];
            #pragma unroll
            for (int i = 0; i < 16; ++i) {
                const float e = E[(sg + 4 * i) * 65 + k];
                accK[i] += e * wk; accV[i] += e * wv;
            }
        }
        #pragma unroll
        for (int i = 0; i < 16; ++i) {
            Km[(sg + 4 * i) * 65 + j] = accK[i];
            Vm[(sg + 4 * i) * 65 + j] = accV[i];
        }
        if (tid < 64) {
            float a = bqkv[tid];
            for (int k = 0; k < 64; ++k) a += E[63 * 65 + k] * wqkvT[k * 192 + tid];
            qv[tid] = a;
        }
    }
    __syncthreads();
    {
        const int h = tid >> 6, k = tid & 63;
        float s = 0.f;
        #pragma unroll
        for (int d = 0; d < 16; ++d) s += qv[h * 16 + d] * Km[k * 65 + h * 16 + d];
        s *= 0.25f;
        float m = s;
        #pragma unroll
        for (int off = 32; off; off >>= 1) m = fmaxf(m, __shfl_xor(m, off));
        const float e = expf(s - m);
        float sum = e;
        #pragma unroll
        for (int off = 32; off; off >>= 1) sum += __shfl_xor(sum, off);
        wsm[h * 64 + k] = e / sum;
    }
    __syncthreads();
    if (tid < 64) {
        const int h = tid >> 4, d = tid & 15;
        float o = 0.f;
        for (int k = 0; k < 64; ++k) o += wsm[h * 64 + k] * Vm[k * 65 + h * 16 + d];
        ov[h * 16 + d] = o;
    }
    __syncthreads();
    if (tid < 64) {
        float a = bo[tid];
        for (int k = 0; k < 64; ++k) a += ov[k] * woT[k * 64 + tid];
        a0last[(size_t)b * 64 + tid] = a;
    }
}

// ---------------------------------------------------------------------------
// Cross-attention (T=48 queries over L=64 enc positions) + out-proj + FC,
// fully fused; writes pred and attn_w directly. One block per batch element.
// Static LDS: 63.4 KB. Buffer reuse: bufE: E->D->O, bufK: K->attn_out,
// bufV: V->hid, bufQ: Q.
// ---------------------------------------------------------------------------
__global__ __launch_bounds__(256) void cross_attn_kernel(
    const float* __restrict__ encout, const float* __restrict__ decout,
    const float* __restrict__ wqkvT, const float* __restrict__ bqkv,
    const float* __restrict__ woT,   const float* __restrict__ bo,
    const float* __restrict__ w1T,   const float* __restrict__ b1,
    const float* __restrict__ W2,    const float* __restrict__ b2,
    float* __restrict__ pred, float* __restrict__ attnw)
{
    __shared__ float bufE[64 * 65];
    __shared__ float bufK[64 * 65];
    __shared__ float bufV[64 * 65];
    __shared__ float bufQ[48 * 65];
    __shared__ float wsm[4 * 64];
    const int b = blockIdx.x, tid = threadIdx.x;

    for (int f = tid; f < 4096; f += 256)
        bufE[(f >> 6) * 65 + (f & 63)] = encout[(size_t)b * 4096 + f];
    __syncthreads();
    {   // K, V projections of enc_out
        const int j = tid & 63, sg = tid >> 6;
        float accK[16], accV[16];
        const float bk = bqkv[64 + j], bv = bqkv[128 + j];
        #pragma unroll
        for (int i = 0; i < 16; ++i) { accK[i] = bk; accV[i] = bv; }
        for (int k = 0; k < 64; ++k) {
            const float wk = wqkvT[k * 192 + 64 + j];
            const float wv = wqkvT[k * 192 + 128 + j];
            #pragma unroll
            for (int i = 0; i < 16; ++i) {
                const float e = bufE[(sg + 4 * i) * 65 + k];
                accK[i] += e * wk; accV[i] += e * wv;
            }
        }
        #pragma unroll
        for (int i = 0; i < 16; ++i) {
            bufK[(sg + 4 * i) * 65 + j] = accK[i];
            bufV[(sg + 4 * i) * 65 + j] = accV[i];
        }
    }
    __syncthreads();
    for (int f = tid; f < 3072; f += 256)   // D over E (E dead)
        bufE[(f >> 6) * 65 + (f & 63)] = decout[(size_t)b * 3072 + f];
    __syncthreads();
    {   // Q projection of dec_out
        const int j = tid & 63, qg = tid >> 6;
        float accQ[12];
        const float bq = bqkv[j];
        #pragma unroll
        for (int i = 0; i < 12; ++i) accQ[i] = bq;
        for (int k = 0; k < 64; ++k) {
            const float wq = wqkvT[k * 192 + j];
            #pragma unroll
            for (int i = 0; i < 12; ++i) accQ[i] += bufE[(qg + 4 * i) * 65 + k] * wq;
        }
        #pragma unroll
        for (int i = 0; i < 12; ++i) bufQ[(qg + 4 * i) * 65 + j] = accQ[i];
    }
    __syncthreads();
    {   // per-head scores + softmax + PV; O -> bufE (D dead)
        const int wv = tid >> 6, lane = tid & 63;
        const int g = lane >> 4, d2 = lane & 15;
        float wacc[12];
        #pragma unroll
        for (int i = 0; i < 12; ++i) wacc[i] = 0.f;
        #pragma unroll 1
        for (int h = 0; h < 4; ++h) {
            #pragma unroll
            for (int i = 0; i < 12; ++i) {
                const int qr = wv + 4 * i;
                float s = 0.f;
                #pragma unroll
                for (int d = 0; d < 16; ++d)
                    s += bufQ[qr * 65 + h * 16 + d] * bufK[lane * 65 + h * 16 + d];
                s *= 0.25f;
                float m = s;
                #pragma unroll
                for (int off = 32; off; off >>= 1) m = fmaxf(m, __shfl_xor(m, off));
                const float e = expf(s - m);
                float sum = e;
                #pragma unroll
                for (int off = 32; off; off >>= 1) sum += __shfl_xor(sum, off);
                const float w = e / sum;
                wacc[i] += 0.25f * w;
                wsm[wv * 64 + lane] = w;
                float p = 0.f;
                #pragma unroll
                for (int kk = 0; kk < 16; ++kk)
                    p += wsm[wv * 64 + g * 16 + kk] * bufV[(g * 16 + kk) * 65 + h * 16 + d2];
                p += __shfl_xor(p, 16); p += __shfl_xor(p, 32);
                if (lane < 16) bufE[qr * 65 + h * 16 + lane] = p;
            }
        }
        #pragma unroll
        for (int i = 0; i < 12; ++i)
            attnw[(size_t)b * 3072 + (wv + 4 * i) * 64 + lane] = wacc[i];
    }
    __syncthreads();
    {   // out-proj: attn_out -> bufK (Km dead)
        const int j = tid & 63, qg = tid >> 6;
        float accA[12];
        const float bov = bo[j];
        #pragma unroll
        for (int i = 0; i < 12; ++i) accA[i] = bov;
        for (int k = 0; k < 64; ++k) {
            const float wo = woT[k * 64 + j];
            #pragma unroll
            for (int i = 0; i < 12; ++i) accA[i] += bufE[(qg + 4 * i) * 65 + k] * wo;
        }
        #pragma unroll
        for (int i = 0; i < 12; ++i) bufK[(qg + 4 * i) * 65 + j] = accA[i];
    }
    __syncthreads();
    {   // FC1 (relu) -> hid in bufV (Vm dead)
        const int m = tid & 31, qg2 = tid >> 5;
        float accH[6];
        const float b1v = b1[m];
        #pragma unroll
        for (int i = 0; i < 6; ++i) accH[i] = b1v;
        for (int j = 0; j < 64; ++j) {
            const float w1v = w1T[j * 32 + m];
            #pragma unroll
            for (int i = 0; i < 6; ++i) accH[i] += bufK[(qg2 + 8 * i) * 65 + j] * w1v;
        }
        #pragma unroll
        for (int i = 0; i < 6; ++i) bufV[(qg2 + 8 * i) * 33 + m] = fmaxf(accH[i], 0.f);
    }
    __syncthreads();
    if (tid < 144) {   // FC2
        const int qr = tid / 3, n = tid - 3 * qr;
        float a = b2[n];
        #pragma unroll
        for (int m2 = 0; m2 < 32; ++m2) a += bufV[qr * 33 + m2] * W2[n * 32 + m2];
        pred[(size_t)b * 144 + tid] = a;
    }
}

// ---------------------------------------------------------------------------
extern "C" void kernel_launch(void* const* d_in, const int* in_sizes, int n_in,
                              void* d_out, int out_size, void* d_ws, size_t ws_size,
                              hipStream_t stream) {
    const float* x      = (const float*)d_in[0];
    const float* target = (const float*)d_in[1];
    const float* eWih0 = (const float*)d_in[2],  *eWhh0 = (const float*)d_in[3];
    const float* ebih0 = (const float*)d_in[4],  *ebhh0 = (const float*)d_in[5];
    const float* eWih1 = (const float*)d_in[6],  *eWhh1 = (const float*)d_in[7];
    const float* ebih1 = (const float*)d_in[8],  *ebhh1 = (const float*)d_in[9];
    const float* dWih0 = (const float*)d_in[10], *dWhh0 = (const float*)d_in[11];
    const float* dbih0 = (const float*)d_in[12], *dbhh0 = (const float*)d_in[13];
    const float* dWih1 = (const float*)d_in[14], *dWhh1 = (const float*)d_in[15];
    const float* dbih1 = (const float*)d_in[16], *dbhh1 = (const float*)d_in[17];
    const float* Wqkv = (const float*)d_in[18], *bqkv = (const float*)d_in[19];
    const float* Wo   = (const float*)d_in[20], *bo   = (const float*)d_in[21];
    const float* W1   = (const float*)d_in[22], *b1   = (const float*)d_in[23];
    const float* W2   = (const float*)d_in[24], *b2   = (const float*)d_in[25];

    float* ws = (float*)d_ws;
    float* hseq1  = ws;                                   // 16,777,216
    float* encout = hseq1  + (size_t)B_ * L_ * H_;        // 16,777,216
    float* decout = encout + (size_t)B_ * L_ * H_;        // 12,582,912
    float* a0last = decout + (size_t)B_ * T_ * H_;        // 262,144
    float* hfin   = a0last + (size_t)B_ * H_;             // 524,288 (2 layers)
    float* cfin   = hfin   + (size_t)2 * B_ * H_;         // 524,288
    float* wtg    = cfin   + (size_t)2 * B_ * H_;         // 4 * 32768
    float* wqkvT  = wtg    + (size_t)4 * 32768;           // 12,288
    float* woT    = wqkvT  + 12288;                       // 4,096
    float* w1T    = woT    + 4096;                        // 2,048

    float* pred  = (float*)d_out;
    float* attnw = pred + (size_t)B_ * T_ * 3;

    // one-time weight transposes
    transpose_w_kernel<<<64, 256, 0, stream>>>(eWih0, eWhh0, wtg + 0 * 32768);
    transpose_w_kernel<<<64, 256, 0, stream>>>(eWih1, eWhh1, wtg + 1 * 32768);
    transpose_w_kernel<<<64, 256, 0, stream>>>(dWih0, dWhh0, wtg + 2 * 32768);
    transpose_w_kernel<<<64, 256, 0, stream>>>(dWih1, dWhh1, wtg + 3 * 32768);
    transpose_aux_kernel<<<72, 256, 0, stream>>>(Wqkv, Wo, W1, wqkvT, woT, w1T);

    const size_t lstmLds = (size_t)(32768 + 16 * 132 + 16 * 260 + 256) * sizeof(float);
    (void)hipFuncSetAttribute((const void*)lstm_layer_kernel,
                              hipFuncAttributeMaxDynamicSharedMemorySize, (int)lstmLds);

    // encoder
    lstm_layer_kernel<<<256, 256, lstmLds, stream>>>(
        x, nullptr, wtg + 0 * 32768, ebih0, ebhh0, nullptr, nullptr,
        hseq1, hfin, cfin, L_, 0);
    lstm_layer_kernel<<<256, 256, lstmLds, stream>>>(
        hseq1, nullptr, wtg + 1 * 32768, ebih1, ebhh1, nullptr, nullptr,
        encout, hfin + (size_t)B_ * H_, cfin + (size_t)B_ * H_, L_, 0);
    // attn0 (only last query position needed)
    attn0_kernel<<<B_, 256, 0, stream>>>(encout, wqkvT, bqkv, woT, bo, a0last);
    // decoder (teacher forcing): dec_in = [attn0_last, target[:, :-1]]
    lstm_layer_kernel<<<256, 256, lstmLds, stream>>>(
        target, a0last, wtg + 2 * 32768, dbih0, dbhh0, hfin, cfin,
        hseq1, nullptr, nullptr, T_, 1);
    lstm_layer_kernel<<<256, 256, lstmLds, stream>>>(
        hseq1, nullptr, wtg + 3 * 32768, dbih1, dbhh1,
        hfin + (size_t)B_ * H_, cfin + (size_t)B_ * H_, decout, nullptr, nullptr, T_, 0);
    // cross-attention + out-proj + FC, fused
    cross_attn_kernel<<<B_, 256, 0, stream>>>(
        encout, decout, wqkvT, bqkv, woT, bo, w1T, b1, W2, b2, pred, attnw);
}

// Round 2
// 1220.213 us; speedup vs baseline: 2.4013x; 2.4013x over previous
//
#include <hip/hip_runtime.h>
#include <hip/hip_bf16.h>
#include <cstddef>

// ---------------------------------------------------------------------------
// LSTMSeq2Seq: B=4096, L=64, T=48, H=64, NH=4, HD=16, NQ=3
// Round 2: LSTM recurrence on MFMA (fp16 2-way split, error-compensated).
// ---------------------------------------------------------------------------

#define B_   4096
#define L_   64
#define T_   48
#define H_   64
#define ROWS 16      // batch rows per LSTM block
#define PADH 136     // halves per A16 row (bank-spread, keeps 16B align)
#define PADR 20      // floats per gb column (mult of 4 -> b128 align)

using half8 = __attribute__((ext_vector_type(8))) _Float16;
using half4 = __attribute__((ext_vector_type(4))) _Float16;
using f32x4 = __attribute__((ext_vector_type(4))) float;

__device__ __forceinline__ float sigf(float x) { return 1.0f / (1.0f + expf(-x)); }

// ---------------------------------------------------------------------------
// Weight split (one-time): whalf[split][gate_row 256][k 128], k = [x|h] concat.
// lo split pre-scaled by 2048 (2^11) so it stays in fp16 normal range.
// ---------------------------------------------------------------------------
__global__ void transpose_w_kernel(const float* __restrict__ Wih,
                                   const float* __restrict__ Whh,
                                   _Float16* __restrict__ out) {
    int idx = blockIdx.x * 256 + threadIdx.x;      // [0, 16384)
    if (idx >= 16384) return;
    int r = idx >> 6, k = idx & 63;
    float wi = Wih[idx];
    _Float16 hi = (_Float16)wi;
    out[r * 128 + k] = hi;
    out[32768 + r * 128 + k] = (_Float16)((wi - (float)hi) * 2048.0f);
    float wh = Whh[idx];
    hi = (_Float16)wh;
    out[r * 128 + 64 + k] = hi;
    out[32768 + r * 128 + 64 + k] = (_Float16)((wh - (float)hi) * 2048.0f);
}

// wqkvT[k][r] (64x192), woT[k][r] (64x64), w1T[k][r] (64x32)  (fp32, for attn)
__global__ void transpose_aux_kernel(const float* __restrict__ Wqkv,
                                     const float* __restrict__ Wo,
                                     const float* __restrict__ W1,
                                     float* __restrict__ wqkvT,
                                     float* __restrict__ woT,
                                     float* __restrict__ w1T) {
    int idx = blockIdx.x * 256 + threadIdx.x;
    if (idx < 12288) {
        int r = idx >> 6, k = idx & 63;
        wqkvT[k * 192 + r] = Wqkv[idx];
    } else if (idx < 16384) {
        int i = idx - 12288; int r = i >> 6, k = i & 63;
        woT[k * 64 + r] = Wo[i];
    } else if (idx < 18432) {
        int i = idx - 16384; int r = i >> 6, k = i & 63;
        w1T[k * 32 + r] = W1[i];
    }
}

// ---------------------------------------------------------------------------
// MFMA LSTM layer. 256 blocks x 256 threads; block owns 16 batch rows.
// Per step: gates(16x256) = A(16x128) @ W^T via mfma_f32_16x16x32_f16,
// 3 split-terms, W fragments resident in VGPRs (128/lane).
// LDS: A16 (fp16 hi/lo, padded rows) + gb (gate staging) ~ 29 KB.
// mode 0: input = inseq[b][t][:];  mode 1: t==0 -> in0[b], else inseq[b][t-1].
// ---------------------------------------------------------------------------
__global__ __launch_bounds__(256, 1) void lstm_mfma_kernel(
    const float* __restrict__ inseq,
    const float* __restrict__ in0,
    const _Float16* __restrict__ whalf,   // [2][256][128]
    const float* __restrict__ bih,
    const float* __restrict__ bhh,
    const float* __restrict__ h0,         // nullable -> zeros
    const float* __restrict__ c0,
    float* __restrict__ outseq,           // [B][S][64]
    float* __restrict__ hfin,             // nullable
    float* __restrict__ cfin,
    int S, int mode)
{
    __shared__ __align__(16) _Float16 A16[2 * 16 * PADH];  // [split][row][k pad]
    __shared__ __align__(16) float gb[256 * PADR];         // [col][row pad]

    const int tid  = threadIdx.x;
    const int w    = tid >> 6;          // wave id: owns cols [w*64, w*64+64)
    const int l    = tid & 63;
    const int lrow = l & 15;            // MFMA: A row / B col / D col
    const int lkg  = l >> 4;            // MFMA k-group; D rows 4*lkg..+3
    const int row0 = blockIdx.x * ROWS;

    // --- W fragments resident in registers: whi/wlo[kt][nt] -----------------
    half8 whi[4][4], wlo[4][4];
    #pragma unroll
    for (int kt = 0; kt < 4; ++kt) {
        #pragma unroll
        for (int nt = 0; nt < 4; ++nt) {
            const int col = w * 64 + nt * 16 + lrow;
            const size_t off = (size_t)col * 128 + kt * 32 + lkg * 8;
            whi[kt][nt] = *(const half8*)&whalf[off];
            wlo[kt][nt] = *(const half8*)&whalf[32768 + off];
        }
    }
    float bsum[4];
    #pragma unroll
    for (int nt = 0; nt < 4; ++nt) {
        const int col = w * 64 + nt * 16 + lrow;
        bsum[nt] = bih[col] + bhh[col];
    }

    // roles: x staging (rx,kx), cell update (ju, rows ru..ru+3)
    const int rx = tid >> 4, kx = (tid & 15) * 4;
    const int ju = tid & 63, ru = (tid >> 6) * 4;

    // --- prologue: stage x(0) | h0, load c0 ---------------------------------
    {
        const float* p0 = (mode == 1) ? (in0 + (size_t)(row0 + rx) * 64 + kx)
                                      : (inseq + (size_t)(row0 + rx) * S * 64 + kx);
        float4 v = *(const float4*)p0;
        half4 hi4, lo4;
        hi4[0] = (_Float16)v.x; lo4[0] = (_Float16)((v.x - (float)hi4[0]) * 2048.f);
        hi4[1] = (_Float16)v.y; lo4[1] = (_Float16)((v.y - (float)hi4[1]) * 2048.f);
        hi4[2] = (_Float16)v.z; lo4[2] = (_Float16)((v.z - (float)hi4[2]) * 2048.f);
        hi4[3] = (_Float16)v.w; lo4[3] = (_Float16)((v.w - (float)hi4[3]) * 2048.f);
        *(half4*)&A16[rx * PADH + kx] = hi4;
        *(half4*)&A16[16 * PADH + rx * PADH + kx] = lo4;
    }
    float c[4], hlast[4] = {0.f, 0.f, 0.f, 0.f};
    #pragma unroll
    for (int i = 0; i < 4; ++i) {
        float hv = h0 ? h0[(size_t)(row0 + ru + i) * 64 + ju] : 0.f;
        _Float16 hh = (_Float16)hv;
        A16[(ru + i) * PADH + 64 + ju] = hh;
        A16[16 * PADH + (ru + i) * PADH + 64 + ju] =
            (_Float16)((hv - (float)hh) * 2048.f);
        c[i] = c0 ? c0[(size_t)(row0 + ru + i) * 64 + ju] : 0.f;
    }

    const int aoffh = lrow * PADH + lkg * 8;

    for (int t = 0; t < S; ++t) {
        __syncthreads();   // A16 (x_t and h_t) ready

        // prefetch next input (written to LDS only in update phase)
        float4 xn;
        if (t + 1 < S) {
            const float* pn = (mode == 1)
                ? (inseq + ((size_t)(row0 + rx) * S + t) * 64 + kx)       // target[t]
                : (inseq + ((size_t)(row0 + rx) * S + (t + 1)) * 64 + kx);
            xn = *(const float4*)pn;
        }

        // --- MFMA phase: 3-term split GEMM ----------------------------------
        f32x4 acc0[4], acc1[4];
        #pragma unroll
        for (int nt = 0; nt < 4; ++nt) {
            acc0[nt] = (f32x4){bsum[nt], bsum[nt], bsum[nt], bsum[nt]};
            acc1[nt] = (f32x4){0.f, 0.f, 0.f, 0.f};
        }
        #pragma unroll
        for (int kt = 0; kt < 4; ++kt) {
            half8 ah = *(const half8*)&A16[aoffh + kt * 32];
            half8 al = *(const half8*)&A16[16 * PADH + aoffh + kt * 32];
            #pragma unroll
            for (int nt = 0; nt < 4; ++nt)
                acc0[nt] = __builtin_amdgcn_mfma_f32_16x16x32_f16(ah, whi[kt][nt], acc0[nt], 0, 0, 0);
            #pragma unroll
            for (int nt = 0; nt < 4; ++nt)
                acc1[nt] = __builtin_amdgcn_mfma_f32_16x16x32_f16(ah, wlo[kt][nt], acc1[nt], 0, 0, 0);
            #pragma unroll
            for (int nt = 0; nt < 4; ++nt)
                acc1[nt] = __builtin_amdgcn_mfma_f32_16x16x32_f16(al, whi[kt][nt], acc1[nt], 0, 0, 0);
        }
        #pragma unroll
        for (int nt = 0; nt < 4; ++nt) {
            f32x4 g = acc0[nt] + acc1[nt] * 4.8828125e-4f;   // + lo-terms * 2^-11
            const int col = w * 64 + nt * 16 + lrow;         // D: col=l&15
            *(f32x4*)&gb[col * PADR + lkg * 4] = g;          // D rows 4*lkg..+3
        }
        __syncthreads();   // gb ready; all A16 reads drained

        // --- cell update: thread owns (col ju, rows ru..ru+3) ---------------
        {
            f32x4 gi = *(const f32x4*)&gb[(0 * 64 + ju) * PADR + ru];
            f32x4 gf = *(const f32x4*)&gb[(1 * 64 + ju) * PADR + ru];
            f32x4 gg = *(const f32x4*)&gb[(2 * 64 + ju) * PADR + ru];
            f32x4 go = *(const f32x4*)&gb[(3 * 64 + ju) * PADR + ru];
            #pragma unroll
            for (int i = 0; i < 4; ++i) {
                c[i] = sigf(gf[i]) * c[i] + sigf(gi[i]) * tanhf(gg[i]);
                float hv = sigf(go[i]) * tanhf(c[i]);
                hlast[i] = hv;
                outseq[((size_t)(row0 + ru + i) * S + t) * 64 + ju] = hv;
                _Float16 hh = (_Float16)hv;
                A16[(ru + i) * PADH + 64 + ju] = hh;
                A16[16 * PADH + (ru + i) * PADH + 64 + ju] =
                    (_Float16)((hv - (float)hh) * 2048.f);
            }
        }
        // stage x(t+1)
        if (t + 1 < S) {
            half4 hi4, lo4;
            hi4[0] = (_Float16)xn.x; lo4[0] = (_Float16)((xn.x - (float)hi4[0]) * 2048.f);
            hi4[1] = (_Float16)xn.y; lo4[1] = (_Float16)((xn.y - (float)hi4[1]) * 2048.f);
            hi4[2] = (_Float16)xn.z; lo4[2] = (_Float16)((xn.z - (float)hi4[2]) * 2048.f);
            hi4[3] = (_Float16)xn.w; lo4[3] = (_Float16)((xn.w - (float)hi4[3]) * 2048.f);
            *(half4*)&A16[rx * PADH + kx] = hi4;
            *(half4*)&A16[16 * PADH + rx * PADH + kx] = lo4;
        }
    }
    if (hfin) {
        #pragma unroll
        for (int i = 0; i < 4; ++i) {
            hfin[(size_t)(row0 + ru + i) * 64 + ju] = hlast[i];
            cfin[(size_t)(row0 + ru + i) * 64 + ju] = c[i];
        }
    }
}

// ---------------------------------------------------------------------------
// Self-attention, last query position only. One block per batch element.
// ---------------------------------------------------------------------------
__global__ __launch_bounds__(256) void attn0_kernel(
    const float* __restrict__ encout,
    const float* __restrict__ wqkvT,   // [64][192]
    const float* __restrict__ bqkv,
    const float* __restrict__ woT,     // [64][64]
    const float* __restrict__ bo,
    float* __restrict__ a0last)        // [B][64]
{
    __shared__ float E[64 * 65];
    __shared__ float Km[64 * 65];
    __shared__ float Vm[64 * 65];
    __shared__ float qv[64];
    __shared__ float wsm[4 * 64];
    __shared__ float ov[64];
    const int b = blockIdx.x, tid = threadIdx.x;

    for (int f = tid; f < 4096; f += 256)
        E[(f >> 6) * 65 + (f & 63)] = encout[(size_t)b * 4096 + f];
    __syncthreads();
    {
        const int j = tid & 63, sg = tid >> 6;
        float accK[16], accV[16];
        const float bk = bqkv[64 + j], bv = bqkv[128 + j];
        #pragma unroll
        for (int i = 0; i < 16; ++i) { accK[i] = bk; accV[i] = bv; }
        for (int k = 0; k < 64; ++k) {
            const float wk = wqkvT[k * 192 + 64 + j];
            const float wv = wqkvT[k * 192 + 128 + j];
            #pragma unroll
            for (int i = 0; i < 16; ++i) {
                const float e = E[(sg + 4 * i) * 65 + k];
                accK[i] += e * wk; accV[i] += e * wv;
            }
        }
        #pragma unroll
        for (int i = 0; i < 16; ++i) {
            Km[(sg + 4 * i) * 65 + j] = accK[i];
            Vm[(sg + 4 * i) * 65 + j] = accV[i];
        }
        if (tid < 64) {
            float a = bqkv[tid];
            for (int k = 0; k < 64; ++k) a += E[63 * 65 + k] * wqkvT[k * 192 + tid];
            qv[tid] = a;
        }
    }
    __syncthreads();
    {
        const int h = tid >> 6, k = tid & 63;
        float s = 0.f;
        #pragma unroll
        for (int d = 0; d < 16; ++d) s += qv[h * 16 + d] * Km[k * 65 + h * 16 + d];
        s *= 0.25f;
        float m = s;
        #pragma unroll
        for (int off = 32; off; off >>= 1) m = fmaxf(m, __shfl_xor(m, off));
        const float e = expf(s - m);
        float sum = e;
        #pragma unroll
        for (int off = 32; off; off >>= 1) sum += __shfl_xor(sum, off);
        wsm[h * 64 + k] = e / sum;
    }
    __syncthreads();
    if (tid < 64) {
        const int h = tid >> 4, d = tid & 15;
        float o = 0.f;
        for (int k = 0; k < 64; ++k) o += wsm[h * 64 + k] * Vm[k * 65 + h * 16 + d];
        ov[h * 16 + d] = o;
    }
    __syncthreads();
    if (tid < 64) {
        float a = bo[tid];
        for (int k = 0; k < 64; ++k) a += ov[k] * woT[k * 64 + tid];
        a0last[(size_t)b * 64 + tid] = a;
    }
}

// ---------------------------------------------------------------------------
// Cross-attention (T=48 q over L=64 kv) + out-proj + FC, fused; one block/b.
// ---------------------------------------------------------------------------
__global__ __launch_bounds__(256) void cross_attn_kernel(
    const float* __restrict__ encout, const float* __restrict__ decout,
    const float* __restrict__ wqkvT, const float* __restrict__ bqkv,
    const float* __restrict__ woT,   const float* __restrict__ bo,
    const float* __restrict__ w1T,   const float* __restrict__ b1,
    const float* __restrict__ W2,    const float* __restrict__ b2,
    float* __restrict__ pred, float* __restrict__ attnw)
{
    __shared__ float bufE[64 * 65];
    __shared__ float bufK[64 * 65];
    __shared__ float bufV[64 * 65];
    __shared__ float bufQ[48 * 65];
    __shared__ float wsm[4 * 64];
    const int b = blockIdx.x, tid = threadIdx.x;

    for (int f = tid; f < 4096; f += 256)
        bufE[(f >> 6) * 65 + (f & 63)] = encout[(size_t)b * 4096 + f];
    __syncthreads();
    {   // K, V projections of enc_out
        const int j = tid & 63, sg = tid >> 6;
        float accK[16], accV[16];
        const float bk = bqkv[64 + j], bv = bqkv[128 + j];
        #pragma unroll
        for (int i = 0; i < 16; ++i) { accK[i] = bk; accV[i] = bv; }
        for (int k = 0; k < 64; ++k) {
            const float wk = wqkvT[k * 192 + 64 + j];
            const float wv = wqkvT[k * 192 + 128 + j];
            #pragma unroll
            for (int i = 0; i < 16; ++i) {
                const float e = bufE[(sg + 4 * i) * 65 + k];
                accK[i] += e * wk; accV[i] += e * wv;
            }
        }
        #pragma unroll
        for (int i = 0; i < 16; ++i) {
            bufK[(sg + 4 * i) * 65 + j] = accK[i];
            bufV[(sg + 4 * i) * 65 + j] = accV[i];
        }
    }
    __syncthreads();
    for (int f = tid; f < 3072; f += 256)   // D over E (E dead)
        bufE[(f >> 6) * 65 + (f & 63)] = decout[(size_t)b * 3072 + f];
    __syncthreads();
    {   // Q projection of dec_out
        const int j = tid & 63, qg = tid >> 6;
        float accQ[12];
        const float bq = bqkv[j];
        #pragma unroll
        for (int i = 0; i < 12; ++i) accQ[i] = bq;
        for (int k = 0; k < 64; ++k) {
            const float wq = wqkvT[k * 192 + j];
            #pragma unroll
            for (int i = 0; i < 12; ++i) accQ[i] += bufE[(qg + 4 * i) * 65 + k] * wq;
        }
        #pragma unroll
        for (int i = 0; i < 12; ++i) bufQ[(qg + 4 * i) * 65 + j] = accQ[i];
    }
    __syncthreads();
    {   // per-head scores + softmax + PV; O -> bufE (D dead)
        const int wv = tid >> 6, lane = tid & 63;
        const int g = lane >> 4, d2 = lane & 15;
        float wacc[12];
        #pragma unroll
        for (int i = 0; i < 12; ++i) wacc[i] = 0.f;
        #pragma unroll 1
        for (int h = 0; h < 4; ++h) {
            #pragma unroll
            for (int i = 0; i < 12; ++i) {
                const int qr = wv + 4 * i;
                float s = 0.f;
                #pragma unroll
                for (int d = 0; d < 16; ++d)
                    s += bufQ[qr * 65 + h * 16 + d] * bufK[lane * 65 + h * 16 + d];
                s *= 0.25f;
                float m = s;
                #pragma unroll
                for (int off = 32; off; off >>= 1) m = fmaxf(m, __shfl_xor(m, off));
                const float e = expf(s - m);
                float sum = e;
                #pragma unroll
                for (int off = 32; off; off >>= 1) sum += __shfl_xor(sum, off);
                const float w = e / sum;
                wacc[i] += 0.25f * w;
                wsm[wv * 64 + lane] = w;
                float p = 0.f;
                #pragma unroll
                for (int kk = 0; kk < 16; ++kk)
                    p += wsm[wv * 64 + g * 16 + kk] * bufV[(g * 16 + kk) * 65 + h * 16 + d2];
                p += __shfl_xor(p, 16); p += __shfl_xor(p, 32);
                if (lane < 16) bufE[qr * 65 + h * 16 + lane] = p;
            }
        }
        #pragma unroll
        for (int i = 0; i < 12; ++i)
            attnw[(size_t)b * 3072 + (wv + 4 * i) * 64 + lane] = wacc[i];
    }
    __syncthreads();
    {   // out-proj: attn_out -> bufK
        const int j = tid & 63, qg = tid >> 6;
        float accA[12];
        const float bov = bo[j];
        #pragma unroll
        for (int i = 0; i < 12; ++i) accA[i] = bov;
        for (int k = 0; k < 64; ++k) {
            const float wo = woT[k * 64 + j];
            #pragma unroll
            for (int i = 0; i < 12; ++i) accA[i] += bufE[(qg + 4 * i) * 65 + k] * wo;
        }
        #pragma unroll
        for (int i = 0; i < 12; ++i) bufK[(qg + 4 * i) * 65 + j] = accA[i];
    }
    __syncthreads();
    {   // FC1 (relu) -> hid in bufV
        const int m = tid & 31, qg2 = tid >> 5;
        float accH[6];
        const float b1v = b1[m];
        #pragma unroll
        for (int i = 0; i < 6; ++i) accH[i] = b1v;
        for (int j = 0; j < 64; ++j) {
            const float w1v = w1T[j * 32 + m];
            #pragma unroll
            for (int i = 0; i < 6; ++i) accH[i] += bufK[(qg2 + 8 * i) * 65 + j] * w1v;
        }
        #pragma unroll
        for (int i = 0; i < 6; ++i) bufV[(qg2 + 8 * i) * 33 + m] = fmaxf(accH[i], 0.f);
    }
    __syncthreads();
    if (tid < 144) {   // FC2
        const int qr = tid / 3, n = tid - 3 * qr;
        float a = b2[n];
        #pragma unroll
        for (int m2 = 0; m2 < 32; ++m2) a += bufV[qr * 33 + m2] * W2[n * 32 + m2];
        pred[(size_t)b * 144 + tid] = a;
    }
}

// ---------------------------------------------------------------------------
extern "C" void kernel_launch(void* const* d_in, const int* in_sizes, int n_in,
                              void* d_out, int out_size, void* d_ws, size_t ws_size,
                              hipStream_t stream) {
    const float* x      = (const float*)d_in[0];
    const float* target = (const float*)d_in[1];
    const float* eWih0 = (const float*)d_in[2],  *eWhh0 = (const float*)d_in[3];
    const float* ebih0 = (const float*)d_in[4],  *ebhh0 = (const float*)d_in[5];
    const float* eWih1 = (const float*)d_in[6],  *eWhh1 = (const float*)d_in[7];
    const float* ebih1 = (const float*)d_in[8],  *ebhh1 = (const float*)d_in[9];
    const float* dWih0 = (const float*)d_in[10], *dWhh0 = (const float*)d_in[11];
    const float* dbih0 = (const float*)d_in[12], *dbhh0 = (const float*)d_in[13];
    const float* dWih1 = (const float*)d_in[14], *dWhh1 = (const float*)d_in[15];
    const float* dbih1 = (const float*)d_in[16], *dbhh1 = (const float*)d_in[17];
    const float* Wqkv = (const float*)d_in[18], *bqkv = (const float*)d_in[19];
    const float* Wo   = (const float*)d_in[20], *bo   = (const float*)d_in[21];
    const float* W1   = (const float*)d_in[22], *b1   = (const float*)d_in[23];
    const float* W2   = (const float*)d_in[24], *b2   = (const float*)d_in[25];

    float* ws = (float*)d_ws;
    float* hseq1  = ws;                                   // B*L*64
    float* encout = hseq1  + (size_t)B_ * L_ * H_;
    float* decout = encout + (size_t)B_ * L_ * H_;
    float* a0last = decout + (size_t)B_ * T_ * H_;
    float* hfin   = a0last + (size_t)B_ * H_;             // 2 layers
    float* cfin   = hfin   + (size_t)2 * B_ * H_;
    float* wtg    = cfin   + (size_t)2 * B_ * H_;         // 4 layers * 32768 floats (as halves)
    float* wqkvT  = wtg    + (size_t)4 * 32768;
    float* woT    = wqkvT  + 12288;
    float* w1T    = woT    + 4096;

    _Float16* wh0 = (_Float16*)(wtg);                     // [2][256][128] per layer
    _Float16* wh1 = wh0 + 65536;
    _Float16* wh2 = wh1 + 65536;
    _Float16* wh3 = wh2 + 65536;

    float* pred  = (float*)d_out;
    float* attnw = pred + (size_t)B_ * T_ * 3;

    // one-time weight preprocessing
    transpose_w_kernel<<<64, 256, 0, stream>>>(eWih0, eWhh0, wh0);
    transpose_w_kernel<<<64, 256, 0, stream>>>(eWih1, eWhh1, wh1);
    transpose_w_kernel<<<64, 256, 0, stream>>>(dWih0, dWhh0, wh2);
    transpose_w_kernel<<<64, 256, 0, stream>>>(dWih1, dWhh1, wh3);
    transpose_aux_kernel<<<72, 256, 0, stream>>>(Wqkv, Wo, W1, wqkvT, woT, w1T);

    // encoder
    lstm_mfma_kernel<<<256, 256, 0, stream>>>(
        x, nullptr, wh0, ebih0, ebhh0, nullptr, nullptr,
        hseq1, hfin, cfin, L_, 0);
    lstm_mfma_kernel<<<256, 256, 0, stream>>>(
        hseq1, nullptr, wh1, ebih1, ebhh1, nullptr, nullptr,
        encout, hfin + (size_t)B_ * H_, cfin + (size_t)B_ * H_, L_, 0);
    // attn0 (only last query position needed)
    attn0_kernel<<<B_, 256, 0, stream>>>(encout, wqkvT, bqkv, woT, bo, a0last);
    // decoder (teacher forcing)
    lstm_mfma_kernel<<<256, 256, 0, stream>>>(
        target, a0last, wh2, dbih0, dbhh0, hfin, cfin,
        hseq1, nullptr, nullptr, T_, 1);
    lstm_mfma_kernel<<<256, 256, 0, stream>>>(
        hseq1, nullptr, wh3, dbih1, dbhh1,
        hfin + (size_t)B_ * H_, cfin + (size_t)B_ * H_, decout, nullptr, nullptr, T_, 0);
    // cross-attention + out-proj + FC, fused
    cross_attn_kernel<<<B_, 256, 0, stream>>>(
        encout, decout, wqkvT, bqkv, woT, bo, w1T, b1, W2, b2, pred, attnw);
}

// Round 3
// 1035.153 us; speedup vs baseline: 2.8306x; 1.1788x over previous
//
#include <hip/hip_runtime.h>
#include <hip/hip_bf16.h>
#include <cstddef>

// ---------------------------------------------------------------------------
// LSTMSeq2Seq: B=4096, L=64, T=48, H=64, NH=4, HD=16, NQ=3
// Round 3: attention pipeline on MFMA (fp16 hi/lo split, error-compensated).
// ---------------------------------------------------------------------------

#define B_   4096
#define L_   64
#define T_   48
#define H_   64
#define ROWS 16
#define PADH 136     // LSTM A16 row pad (halves)
#define PADR 20      // LSTM gb col pad (floats)

using half8 = __attribute__((ext_vector_type(8))) _Float16;
using half4 = __attribute__((ext_vector_type(4))) _Float16;
using f32x4 = __attribute__((ext_vector_type(4))) float;

__device__ __forceinline__ float sigf(float x) { return 1.0f / (1.0f + expf(-x)); }

#define IC_ 4.8828125e-4f   // 2^-11

// ---------------------------------------------------------------------------
// LSTM weight split (one-time): whalf[split][gate_row 256][k 128]
// ---------------------------------------------------------------------------
__global__ void transpose_w_kernel(const float* __restrict__ Wih,
                                   const float* __restrict__ Whh,
                                   _Float16* __restrict__ out) {
    int idx = blockIdx.x * 256 + threadIdx.x;
    if (idx >= 16384) return;
    int r = idx >> 6, k = idx & 63;
    float wi = Wih[idx];
    _Float16 hi = (_Float16)wi;
    out[r * 128 + k] = hi;
    out[32768 + r * 128 + k] = (_Float16)((wi - (float)hi) * 2048.0f);
    float wh = Whh[idx];
    hi = (_Float16)wh;
    out[r * 128 + 64 + k] = hi;
    out[32768 + r * 128 + 64 + k] = (_Float16)((wh - (float)hi) * 2048.0f);
}

// Attention weight splits: wqkvh[2][192][64], woh[2][64][64], w1h[2][32][64]
__global__ void split_aux_kernel(const float* __restrict__ Wqkv,
                                 const float* __restrict__ Wo,
                                 const float* __restrict__ W1,
                                 _Float16* __restrict__ wqkvh,
                                 _Float16* __restrict__ woh,
                                 _Float16* __restrict__ w1h) {
    int idx = blockIdx.x * 256 + threadIdx.x;
    if (idx < 12288) {
        float v = Wqkv[idx]; _Float16 h = (_Float16)v;
        wqkvh[idx] = h; wqkvh[12288 + idx] = (_Float16)((v - (float)h) * 2048.f);
    } else if (idx < 16384) {
        int i = idx - 12288;
        float v = Wo[i]; _Float16 h = (_Float16)v;
        woh[i] = h; woh[4096 + i] = (_Float16)((v - (float)h) * 2048.f);
    } else if (idx < 18432) {
        int i = idx - 16384;
        float v = W1[i]; _Float16 h = (_Float16)v;
        w1h[i] = h; w1h[2048 + i] = (_Float16)((v - (float)h) * 2048.f);
    }
}

// ---------------------------------------------------------------------------
// MFMA LSTM layer (unchanged from round 2).
// ---------------------------------------------------------------------------
__global__ __launch_bounds__(256, 1) void lstm_mfma_kernel(
    const float* __restrict__ inseq,
    const float* __restrict__ in0,
    const _Float16* __restrict__ whalf,
    const float* __restrict__ bih,
    const float* __restrict__ bhh,
    const float* __restrict__ h0,
    const float* __restrict__ c0,
    float* __restrict__ outseq,
    float* __restrict__ hfin,
    float* __restrict__ cfin,
    int S, int mode)
{
    __shared__ __align__(16) _Float16 A16[2 * 16 * PADH];
    __shared__ __align__(16) float gb[256 * PADR];

    const int tid  = threadIdx.x;
    const int w    = tid >> 6;
    const int l    = tid & 63;
    const int lrow = l & 15;
    const int lkg  = l >> 4;
    const int row0 = blockIdx.x * ROWS;

    half8 whi[4][4], wlo[4][4];
    #pragma unroll
    for (int kt = 0; kt < 4; ++kt) {
        #pragma unroll
        for (int nt = 0; nt < 4; ++nt) {
            const int col = w * 64 + nt * 16 + lrow;
            const size_t off = (size_t)col * 128 + kt * 32 + lkg * 8;
            whi[kt][nt] = *(const half8*)&whalf[off];
            wlo[kt][nt] = *(const half8*)&whalf[32768 + off];
        }
    }
    float bsum[4];
    #pragma unroll
    for (int nt = 0; nt < 4; ++nt) {
        const int col = w * 64 + nt * 16 + lrow;
        bsum[nt] = bih[col] + bhh[col];
    }

    const int rx = tid >> 4, kx = (tid & 15) * 4;
    const int ju = tid & 63, ru = (tid >> 6) * 4;

    {
        const float* p0 = (mode == 1) ? (in0 + (size_t)(row0 + rx) * 64 + kx)
                                      : (inseq + (size_t)(row0 + rx) * S * 64 + kx);
        float4 v = *(const float4*)p0;
        half4 hi4, lo4;
        hi4[0] = (_Float16)v.x; lo4[0] = (_Float16)((v.x - (float)hi4[0]) * 2048.f);
        hi4[1] = (_Float16)v.y; lo4[1] = (_Float16)((v.y - (float)hi4[1]) * 2048.f);
        hi4[2] = (_Float16)v.z; lo4[2] = (_Float16)((v.z - (float)hi4[2]) * 2048.f);
        hi4[3] = (_Float16)v.w; lo4[3] = (_Float16)((v.w - (float)hi4[3]) * 2048.f);
        *(half4*)&A16[rx * PADH + kx] = hi4;
        *(half4*)&A16[16 * PADH + rx * PADH + kx] = lo4;
    }
    float c[4], hlast[4] = {0.f, 0.f, 0.f, 0.f};
    #pragma unroll
    for (int i = 0; i < 4; ++i) {
        float hv = h0 ? h0[(size_t)(row0 + ru + i) * 64 + ju] : 0.f;
        _Float16 hh = (_Float16)hv;
        A16[(ru + i) * PADH + 64 + ju] = hh;
        A16[16 * PADH + (ru + i) * PADH + 64 + ju] =
            (_Float16)((hv - (float)hh) * 2048.f);
        c[i] = c0 ? c0[(size_t)(row0 + ru + i) * 64 + ju] : 0.f;
    }

    const int aoffh = lrow * PADH + lkg * 8;

    for (int t = 0; t < S; ++t) {
        __syncthreads();

        float4 xn;
        if (t + 1 < S) {
            const float* pn = (mode == 1)
                ? (inseq + ((size_t)(row0 + rx) * S + t) * 64 + kx)
                : (inseq + ((size_t)(row0 + rx) * S + (t + 1)) * 64 + kx);
            xn = *(const float4*)pn;
        }

        f32x4 acc0[4], acc1[4];
        #pragma unroll
        for (int nt = 0; nt < 4; ++nt) {
            acc0[nt] = (f32x4){bsum[nt], bsum[nt], bsum[nt], bsum[nt]};
            acc1[nt] = (f32x4){0.f, 0.f, 0.f, 0.f};
        }
        #pragma unroll
        for (int kt = 0; kt < 4; ++kt) {
            half8 ah = *(const half8*)&A16[aoffh + kt * 32];
            half8 al = *(const half8*)&A16[16 * PADH + aoffh + kt * 32];
            #pragma unroll
            for (int nt = 0; nt < 4; ++nt)
                acc0[nt] = __builtin_amdgcn_mfma_f32_16x16x32_f16(ah, whi[kt][nt], acc0[nt], 0, 0, 0);
            #pragma unroll
            for (int nt = 0; nt < 4; ++nt)
                acc1[nt] = __builtin_amdgcn_mfma_f32_16x16x32_f16(ah, wlo[kt][nt], acc1[nt], 0, 0, 0);
            #pragma unroll
            for (int nt = 0; nt < 4; ++nt)
                acc1[nt] = __builtin_amdgcn_mfma_f32_16x16x32_f16(al, whi[kt][nt], acc1[nt], 0, 0, 0);
        }
        #pragma unroll
        for (int nt = 0; nt < 4; ++nt) {
            f32x4 g = acc0[nt] + acc1[nt] * IC_;
            const int col = w * 64 + nt * 16 + lrow;
            *(f32x4*)&gb[col * PADR + lkg * 4] = g;
        }
        __syncthreads();

        {
            f32x4 gi = *(const f32x4*)&gb[(0 * 64 + ju) * PADR + ru];
            f32x4 gf = *(const f32x4*)&gb[(1 * 64 + ju) * PADR + ru];
            f32x4 gg = *(const f32x4*)&gb[(2 * 64 + ju) * PADR + ru];
            f32x4 go = *(const f32x4*)&gb[(3 * 64 + ju) * PADR + ru];
            #pragma unroll
            for (int i = 0; i < 4; ++i) {
                c[i] = sigf(gf[i]) * c[i] + sigf(gi[i]) * tanhf(gg[i]);
                float hv = sigf(go[i]) * tanhf(c[i]);
                hlast[i] = hv;
                outseq[((size_t)(row0 + ru + i) * S + t) * 64 + ju] = hv;
                _Float16 hh = (_Float16)hv;
                A16[(ru + i) * PADH + 64 + ju] = hh;
                A16[16 * PADH + (ru + i) * PADH + 64 + ju] =
                    (_Float16)((hv - (float)hh) * 2048.f);
            }
        }
        if (t + 1 < S) {
            half4 hi4, lo4;
            hi4[0] = (_Float16)xn.x; lo4[0] = (_Float16)((xn.x - (float)hi4[0]) * 2048.f);
            hi4[1] = (_Float16)xn.y; lo4[1] = (_Float16)((xn.y - (float)hi4[1]) * 2048.f);
            hi4[2] = (_Float16)xn.z; lo4[2] = (_Float16)((xn.z - (float)hi4[2]) * 2048.f);
            hi4[3] = (_Float16)xn.w; lo4[3] = (_Float16)((xn.w - (float)hi4[3]) * 2048.f);
            *(half4*)&A16[rx * PADH + kx] = hi4;
            *(half4*)&A16[16 * PADH + rx * PADH + kx] = lo4;
        }
    }
    if (hfin) {
        #pragma unroll
        for (int i = 0; i < 4; ++i) {
            hfin[(size_t)(row0 + ru + i) * 64 + ju] = hlast[i];
            cfin[(size_t)(row0 + ru + i) * 64 + ju] = c[i];
        }
    }
}

// ---------------------------------------------------------------------------
// Helper: stage a fp32 row-block into hi/lo fp16 LDS planes [R][72]
// ---------------------------------------------------------------------------
__device__ __forceinline__ void stage_split(const float* __restrict__ src,
                                            _Float16* dst, int plane,
                                            int row, int c0) {
    #pragma unroll
    for (int u = 0; u < 4; ++u) {
        float4 v = *(const float4*)(src + u * 4);
        half4 hi, lo;
        hi[0] = (_Float16)v.x; lo[0] = (_Float16)((v.x - (float)hi[0]) * 2048.f);
        hi[1] = (_Float16)v.y; lo[1] = (_Float16)((v.y - (float)hi[1]) * 2048.f);
        hi[2] = (_Float16)v.z; lo[2] = (_Float16)((v.z - (float)hi[2]) * 2048.f);
        hi[3] = (_Float16)v.w; lo[3] = (_Float16)((v.w - (float)hi[3]) * 2048.f);
        *(half4*)&dst[row * 72 + c0 + u * 4] = hi;
        *(half4*)&dst[plane + row * 72 + c0 + u * 4] = lo;
    }
}

// ---------------------------------------------------------------------------
// Self-attention, last query only. K/V proj on MFMA; tiny VALU tail.
// One block per b. Static LDS ~47KB.
// ---------------------------------------------------------------------------
__global__ __launch_bounds__(256) void attn0_mfma(
    const float* __restrict__ encout,
    const _Float16* __restrict__ wqkvh,
    const float* __restrict__ bqkv,
    const float* __restrict__ Wqkv,     // fp32, for q_last
    const float* __restrict__ Wo,       // fp32, for out-proj tail
    const float* __restrict__ bo,
    float* __restrict__ a0last)
{
    __shared__ __align__(16) _Float16 E16[2 * 4608];
    __shared__ __align__(16) _Float16 K16[2 * 4608];
    __shared__ __align__(16) _Float16 V16[4608];
    __shared__ float qv[64];
    __shared__ float wrow[4 * 68];
    __shared__ float ov[64];

    const int b = blockIdx.x, tid = threadIdx.x;
    const int w = tid >> 6, l = tid & 63, lr = l & 15, lkg = l >> 4;

    {   // stage E
        int row = tid >> 2, c0 = (tid & 3) * 16;
        stage_split(encout + (size_t)b * 4096 + row * 64 + c0, E16, 4608, row, c0);
    }
    __syncthreads();

    // K/V projection tiles (8 tiles, 2 per wave)
    for (int tt = w; tt < 8; tt += 4) {
        const int kind = (tt < 4) ? 0 : 1;
        const int mrow = (kind ? tt - 4 : tt) * 16;
        const int wrowB = kind ? 128 : 64;
        half8 ah[2], al[2];
        #pragma unroll
        for (int kt = 0; kt < 2; ++kt) {
            int ao = (mrow + lr) * 72 + kt * 32 + lkg * 8;
            ah[kt] = *(const half8*)&E16[ao];
            al[kt] = *(const half8*)&E16[4608 + ao];
        }
        #pragma unroll
        for (int nt = 0; nt < 4; ++nt) {
            const int col = nt * 16 + lr;
            const float bv = bqkv[wrowB + col];
            f32x4 a0 = (f32x4){bv, bv, bv, bv};
            f32x4 a1 = (f32x4){0.f, 0.f, 0.f, 0.f};
            #pragma unroll
            for (int kt = 0; kt < 2; ++kt) {
                const _Float16* wp = wqkvh + (size_t)(wrowB + col) * 64 + kt * 32 + lkg * 8;
                half8 bh = *(const half8*)wp;
                half8 bl = *(const half8*)(wp + 12288);
                a0 = __builtin_amdgcn_mfma_f32_16x16x32_f16(ah[kt], bh, a0, 0, 0, 0);
                a1 = __builtin_amdgcn_mfma_f32_16x16x32_f16(ah[kt], bl, a1, 0, 0, 0);
                a1 = __builtin_amdgcn_mfma_f32_16x16x32_f16(al[kt], bh, a1, 0, 0, 0);
            }
            #pragma unroll
            for (int i = 0; i < 4; ++i) {
                float g = a0[i] + a1[i] * IC_;
                int r = mrow + lkg * 4 + i;
                if (kind == 0) {
                    _Float16 gh = (_Float16)g;
                    K16[r * 72 + col] = gh;
                    K16[4608 + r * 72 + col] = (_Float16)((g - (float)gh) * 2048.f);
                } else {
                    V16[r * 72 + col] = (_Float16)g;
                }
            }
        }
    }
    // q_last (wave 3, after its 2 tiles)
    if (w == 3) {
        float a = bqkv[l];
        for (int k = 0; k < 64; ++k) {
            float e = (float)E16[63 * 72 + k] + (float)E16[4608 + 63 * 72 + k] * IC_;
            a += e * Wqkv[l * 64 + k];
        }
        qv[l] = a;
    }
    __syncthreads();

    {   // scores + softmax: wave = head, lane = kv
        const int h = w, kv = l;
        float s = 0.f;
        #pragma unroll
        for (int d = 0; d < 16; ++d) {
            float kk = (float)K16[kv * 72 + h * 16 + d]
                     + (float)K16[4608 + kv * 72 + h * 16 + d] * IC_;
            s += qv[h * 16 + d] * kk;
        }
        s *= 0.25f;
        float m = s;
        #pragma unroll
        for (int off = 32; off; off >>= 1) m = fmaxf(m, __shfl_xor(m, off));
        float e = expf(s - m);
        float sum = e;
        #pragma unroll
        for (int off = 32; off; off >>= 1) sum += __shfl_xor(sum, off);
        wrow[h * 68 + kv] = e / sum;
    }
    __syncthreads();
    if (tid < 64) {   // PV
        const int h = tid >> 4, d = tid & 15;
        float o = 0.f;
        for (int kv = 0; kv < 64; ++kv)
            o += wrow[h * 68 + kv] * (float)V16[kv * 72 + h * 16 + d];
        ov[tid] = o;
    }
    __syncthreads();
    if (tid < 64) {   // out-proj
        float a = bo[tid];
        for (int k = 0; k < 64; ++k) a += ov[k] * Wo[tid * 64 + k];
        a0last[(size_t)b * 64 + tid] = a;
    }
}

// ---------------------------------------------------------------------------
// Cross-attention + out-proj + FC, all-MFMA. Grid 1024, 4 b per block.
// Dynamic LDS 73728 B, phase-aliased. 2 blocks/CU.
// ---------------------------------------------------------------------------
__global__ __launch_bounds__(256, 2) void cross_attn_mfma(
    const float* __restrict__ encout, const float* __restrict__ decout,
    const _Float16* __restrict__ wqkvh, const float* __restrict__ bqkv,
    const _Float16* __restrict__ woh,   const float* __restrict__ bo,
    const _Float16* __restrict__ w1h,   const float* __restrict__ b1,
    const float* __restrict__ W2,       const float* __restrict__ b2,
    float* __restrict__ pred, float* __restrict__ attnw)
{
    extern __shared__ __align__(16) char smem[];
    _Float16* E16  = (_Float16*)(smem);            // [2][4608]
    _Float16* D16  = (_Float16*)(smem + 18432);    // [2][3456]
    _Float16* VT16 = (_Float16*)(smem + 32256);    // [4608] single, [d][kv]
    _Float16* K16  = (_Float16*)(smem + 41472);    // [2][4608]
    _Float16* Q16  = (_Float16*)(smem + 59904);    // [2][3456]
    _Float16* W16  = (_Float16*)(smem + 41472);    // [4][3456] (over K16,Q16)
    _Float16* AO16 = (_Float16*)(smem);            // [3456] (over E16)
    float*    WACC = (float*)(smem + 18432);       // [48*65] (over D16)
    _Float16* O16  = (_Float16*)(smem + 32256);    // [3456] (over VT16)
    float*    H1   = (float*)(smem + 6912);        // [48*36] (over E16 hi tail)

    const int tid = threadIdx.x;
    const int w = tid >> 6, l = tid & 63, lr = l & 15, lkg = l >> 4;

    for (int ib = 0; ib < 4; ++ib) {
        const int b = blockIdx.x * 4 + ib;

        // ---- P0: stage E, D as hi/lo fp16 --------------------------------
        {
            int row = tid >> 2, c0 = (tid & 3) * 16;
            stage_split(encout + (size_t)b * 4096 + row * 64 + c0, E16, 4608, row, c0);
            if (row < 48)
                stage_split(decout + (size_t)b * 3072 + row * 64 + c0, D16, 3456, row, c0);
        }
        __syncthreads();

        // ---- P12: K/V/Q projection tiles (11 tiles over 4 waves) ---------
        for (int tt = w; tt < 11; tt += 4) {
            const int kind = (tt < 4) ? 0 : ((tt < 8) ? 1 : 2);
            const int mrow = ((kind == 0) ? tt : (kind == 1) ? tt - 4 : tt - 8) * 16;
            const int wrowB = (kind == 0) ? 64 : ((kind == 1) ? 128 : 0);
            const _Float16* S = (kind == 2) ? D16 : E16;
            const int plane = (kind == 2) ? 3456 : 4608;
            half8 ah[2], al[2];
            #pragma unroll
            for (int kt = 0; kt < 2; ++kt) {
                int ao = (mrow + lr) * 72 + kt * 32 + lkg * 8;
                ah[kt] = *(const half8*)&S[ao];
                al[kt] = *(const half8*)&S[plane + ao];
            }
            #pragma unroll
            for (int nt = 0; nt < 4; ++nt) {
                const int col = nt * 16 + lr;
                const float bv = bqkv[wrowB + col];
                f32x4 a0 = (f32x4){bv, bv, bv, bv};
                f32x4 a1 = (f32x4){0.f, 0.f, 0.f, 0.f};
                #pragma unroll
                for (int kt = 0; kt < 2; ++kt) {
                    const _Float16* wp = wqkvh + (size_t)(wrowB + col) * 64 + kt * 32 + lkg * 8;
                    half8 bh = *(const half8*)wp;
                    half8 bl = *(const half8*)(wp + 12288);
                    a0 = __builtin_amdgcn_mfma_f32_16x16x32_f16(ah[kt], bh, a0, 0, 0, 0);
                    a1 = __builtin_amdgcn_mfma_f32_16x16x32_f16(ah[kt], bl, a1, 0, 0, 0);
                    a1 = __builtin_amdgcn_mfma_f32_16x16x32_f16(al[kt], bh, a1, 0, 0, 0);
                }
                #pragma unroll
                for (int i = 0; i < 4; ++i) {
                    float g = a0[i] + a1[i] * IC_;
                    int r = mrow + lkg * 4 + i;
                    if (kind == 0) {
                        _Float16 gh = (_Float16)g;
                        K16[r * 72 + col] = gh;
                        K16[4608 + r * 72 + col] = (_Float16)((g - (float)gh) * 2048.f);
                    } else if (kind == 2) {
                        _Float16 gh = (_Float16)g;
                        Q16[r * 72 + col] = gh;
                        Q16[3456 + r * 72 + col] = (_Float16)((g - (float)gh) * 2048.f);
                    } else {
                        VT16[col * 72 + r] = (_Float16)g;   // transposed, single
                    }
                }
            }
        }
        __syncthreads();

        // ---- P3a: zero WACC; scores (zero-padded K=32 MFMA) + softmax ----
        for (int i2 = tid; i2 < 48 * 65; i2 += 256) WACC[i2] = 0.f;
        f32x4 s[3][4];
        {
            const int h = w;
            const half8 z = {0, 0, 0, 0, 0, 0, 0, 0};
            half8 kbh[4], kbl[4];
            #pragma unroll
            for (int kvt = 0; kvt < 4; ++kvt) {
                if (lkg < 2) {
                    int off = (kvt * 16 + lr) * 72 + h * 16 + lkg * 8;
                    kbh[kvt] = *(const half8*)&K16[off];
                    kbl[kvt] = *(const half8*)&K16[4608 + off];
                } else { kbh[kvt] = z; kbl[kvt] = z; }
            }
            #pragma unroll
            for (int qt = 0; qt < 3; ++qt) {
                half8 qh = z, ql = z;
                if (lkg < 2) {
                    int off = (qt * 16 + lr) * 72 + h * 16 + lkg * 8;
                    qh = *(const half8*)&Q16[off];
                    ql = *(const half8*)&Q16[3456 + off];
                }
                #pragma unroll
                for (int kvt = 0; kvt < 4; ++kvt) {
                    f32x4 a0 = (f32x4){0.f, 0.f, 0.f, 0.f};
                    f32x4 a1 = (f32x4){0.f, 0.f, 0.f, 0.f};
                    a0 = __builtin_amdgcn_mfma_f32_16x16x32_f16(qh, kbh[kvt], a0, 0, 0, 0);
                    a1 = __builtin_amdgcn_mfma_f32_16x16x32_f16(qh, kbl[kvt], a1, 0, 0, 0);
                    a1 = __builtin_amdgcn_mfma_f32_16x16x32_f16(ql, kbh[kvt], a1, 0, 0, 0);
                    s[qt][kvt] = (a0 + a1 * IC_) * 0.25f;
                }
                #pragma unroll
                for (int i = 0; i < 4; ++i) {
                    float m = fmaxf(fmaxf(s[qt][0][i], s[qt][1][i]),
                                    fmaxf(s[qt][2][i], s[qt][3][i]));
                    m = fmaxf(m, __shfl_xor(m, 1));
                    m = fmaxf(m, __shfl_xor(m, 2));
                    m = fmaxf(m, __shfl_xor(m, 4));
                    m = fmaxf(m, __shfl_xor(m, 8));
                    float sum = 0.f;
                    #pragma unroll
                    for (int kvt = 0; kvt < 4; ++kvt) {
                        float e = expf(s[qt][kvt][i] - m);
                        s[qt][kvt][i] = e;
                        sum += e;
                    }
                    sum += __shfl_xor(sum, 1);
                    sum += __shfl_xor(sum, 2);
                    sum += __shfl_xor(sum, 4);
                    sum += __shfl_xor(sum, 8);
                    float r = 1.0f / sum;
                    #pragma unroll
                    for (int kvt = 0; kvt < 4; ++kvt) s[qt][kvt][i] *= r;
                }
            }
        }
        __syncthreads();

        // ---- P3b: write w (fp16) + accumulate attnw mean -----------------
        {
            const int h = w;
            #pragma unroll
            for (int qt = 0; qt < 3; ++qt)
                #pragma unroll
                for (int kvt = 0; kvt < 4; ++kvt)
                    #pragma unroll
                    for (int i = 0; i < 4; ++i) {
                        float wv = s[qt][kvt][i];
                        int q = qt * 16 + lkg * 4 + i, kv = kvt * 16 + lr;
                        W16[h * 3456 + q * 72 + kv] = (_Float16)wv;
                        atomicAdd(&WACC[q * 65 + kv], 0.25f * wv);
                    }
        }
        __syncthreads();

        // ---- P4: PV (wave = head) ----------------------------------------
        {
            const int h = w;
            half8 vb[2];
            #pragma unroll
            for (int kt = 0; kt < 2; ++kt)
                vb[kt] = *(const half8*)&VT16[(h * 16 + lr) * 72 + kt * 32 + lkg * 8];
            #pragma unroll
            for (int qt = 0; qt < 3; ++qt) {
                half8 wa0 = *(const half8*)&W16[h * 3456 + (qt * 16 + lr) * 72 + lkg * 8];
                half8 wa1 = *(const half8*)&W16[h * 3456 + (qt * 16 + lr) * 72 + 32 + lkg * 8];
                f32x4 acc = (f32x4){0.f, 0.f, 0.f, 0.f};
                acc = __builtin_amdgcn_mfma_f32_16x16x32_f16(wa0, vb[0], acc, 0, 0, 0);
                acc = __builtin_amdgcn_mfma_f32_16x16x32_f16(wa1, vb[1], acc, 0, 0, 0);
                #pragma unroll
                for (int i = 0; i < 4; ++i)
                    AO16[(qt * 16 + lkg * 4 + i) * 72 + h * 16 + lr] = (_Float16)acc[i];
            }
        }
        __syncthreads();

        // ---- P5: out-proj (waves 0-2) + attnw store (wave 3) -------------
        if (w < 3) {
            const int mrow = w * 16;
            half8 ah2[2];
            #pragma unroll
            for (int kt = 0; kt < 2; ++kt)
                ah2[kt] = *(const half8*)&AO16[(mrow + lr) * 72 + kt * 32 + lkg * 8];
            #pragma unroll
            for (int nt = 0; nt < 4; ++nt) {
                const int col = nt * 16 + lr;
                const float bv = bo[col];
                f32x4 a0 = (f32x4){bv, bv, bv, bv};
                f32x4 a1 = (f32x4){0.f, 0.f, 0.f, 0.f};
                #pragma unroll
                for (int kt = 0; kt < 2; ++kt) {
                    const _Float16* wp = woh + (size_t)col * 64 + kt * 32 + lkg * 8;
                    half8 bh = *(const half8*)wp;
                    half8 bl = *(const half8*)(wp + 4096);
                    a0 = __builtin_amdgcn_mfma_f32_16x16x32_f16(ah2[kt], bh, a0, 0, 0, 0);
                    a1 = __builtin_amdgcn_mfma_f32_16x16x32_f16(ah2[kt], bl, a1, 0, 0, 0);
                }
                #pragma unroll
                for (int i = 0; i < 4; ++i) {
                    float g = a0[i] + a1[i] * IC_;
                    O16[(mrow + lkg * 4 + i) * 72 + col] = (_Float16)g;
                }
            }
        } else {
            for (int idx = l; idx < 3072; idx += 64)
                attnw[(size_t)b * 3072 + idx] = WACC[(idx >> 6) * 65 + (idx & 63)];
        }
        __syncthreads();

        // ---- P6: FC1 + relu (waves 0-2) ----------------------------------
        if (w < 3) {
            const int mrow = w * 16;
            half8 ah2[2];
            #pragma unroll
            for (int kt = 0; kt < 2; ++kt)
                ah2[kt] = *(const half8*)&O16[(mrow + lr) * 72 + kt * 32 + lkg * 8];
            #pragma unroll
            for (int nt = 0; nt < 2; ++nt) {
                const int col = nt * 16 + lr;
                const float bv = b1[col];
                f32x4 a0 = (f32x4){bv, bv, bv, bv};
                f32x4 a1 = (f32x4){0.f, 0.f, 0.f, 0.f};
                #pragma unroll
                for (int kt = 0; kt < 2; ++kt) {
                    const _Float16* wp = w1h + (size_t)col * 64 + kt * 32 + lkg * 8;
                    half8 bh = *(const half8*)wp;
                    half8 bl = *(const half8*)(wp + 2048);
                    a0 = __builtin_amdgcn_mfma_f32_16x16x32_f16(ah2[kt], bh, a0, 0, 0, 0);
                    a1 = __builtin_amdgcn_mfma_f32_16x16x32_f16(ah2[kt], bl, a1, 0, 0, 0);
                }
                #pragma unroll
                for (int i = 0; i < 4; ++i) {
                    float g = fmaxf(a0[i] + a1[i] * IC_, 0.f);
                    H1[(mrow + lkg * 4 + i) * 36 + col] = g;
                }
            }
        }
        __syncthreads();

        // ---- P7: FC2 ------------------------------------------------------
        if (tid < 144) {
            int q = tid / 3, n = tid - q * 3;
            float a = b2[n];
            #pragma unroll
            for (int m2 = 0; m2 < 32; ++m2) a += H1[q * 36 + m2] * W2[n * 32 + m2];
            pred[(size_t)b * 144 + q * 3 + n] = a;
        }
        __syncthreads();
    }
}

// ---------------------------------------------------------------------------
extern "C" void kernel_launch(void* const* d_in, const int* in_sizes, int n_in,
                              void* d_out, int out_size, void* d_ws, size_t ws_size,
                              hipStream_t stream) {
    const float* x      = (const float*)d_in[0];
    const float* target = (const float*)d_in[1];
    const float* eWih0 = (const float*)d_in[2],  *eWhh0 = (const float*)d_in[3];
    const float* ebih0 = (const float*)d_in[4],  *ebhh0 = (const float*)d_in[5];
    const float* eWih1 = (const float*)d_in[6],  *eWhh1 = (const float*)d_in[7];
    const float* ebih1 = (const float*)d_in[8],  *ebhh1 = (const float*)d_in[9];
    const float* dWih0 = (const float*)d_in[10], *dWhh0 = (const float*)d_in[11];
    const float* dbih0 = (const float*)d_in[12], *dbhh0 = (const float*)d_in[13];
    const float* dWih1 = (const float*)d_in[14], *dWhh1 = (const float*)d_in[15];
    const float* dbih1 = (const float*)d_in[16], *dbhh1 = (const float*)d_in[17];
    const float* Wqkv = (const float*)d_in[18], *bqkv = (const float*)d_in[19];
    const float* Wo   = (const float*)d_in[20], *bo   = (const float*)d_in[21];
    const float* W1   = (const float*)d_in[22], *b1   = (const float*)d_in[23];
    const float* W2   = (const float*)d_in[24], *b2   = (const float*)d_in[25];

    float* ws = (float*)d_ws;
    float* hseq1  = ws;
    float* encout = hseq1  + (size_t)B_ * L_ * H_;
    float* decout = encout + (size_t)B_ * L_ * H_;
    float* a0last = decout + (size_t)B_ * T_ * H_;
    float* hfin   = a0last + (size_t)B_ * H_;
    float* cfin   = hfin   + (size_t)2 * B_ * H_;
    float* wtg    = cfin   + (size_t)2 * B_ * H_;         // 4 * 32768 floats (halves)
    float* auxw   = wtg    + (size_t)4 * 32768;

    _Float16* wh0 = (_Float16*)(wtg);
    _Float16* wh1 = wh0 + 65536;
    _Float16* wh2 = wh1 + 65536;
    _Float16* wh3 = wh2 + 65536;
    _Float16* wqkvh = (_Float16*)auxw;        // [2][192][64] = 24576 halves
    _Float16* woh   = wqkvh + 24576;          // [2][64][64]  = 8192
    _Float16* w1h   = woh + 8192;             // [2][32][64]  = 4096

    float* pred  = (float*)d_out;
    float* attnw = pred + (size_t)B_ * T_ * 3;

    transpose_w_kernel<<<64, 256, 0, stream>>>(eWih0, eWhh0, wh0);
    transpose_w_kernel<<<64, 256, 0, stream>>>(eWih1, eWhh1, wh1);
    transpose_w_kernel<<<64, 256, 0, stream>>>(dWih0, dWhh0, wh2);
    transpose_w_kernel<<<64, 256, 0, stream>>>(dWih1, dWhh1, wh3);
    split_aux_kernel<<<72, 256, 0, stream>>>(Wqkv, Wo, W1, wqkvh, woh, w1h);

    // encoder
    lstm_mfma_kernel<<<256, 256, 0, stream>>>(
        x, nullptr, wh0, ebih0, ebhh0, nullptr, nullptr,
        hseq1, hfin, cfin, L_, 0);
    lstm_mfma_kernel<<<256, 256, 0, stream>>>(
        hseq1, nullptr, wh1, ebih1, ebhh1, nullptr, nullptr,
        encout, hfin + (size_t)B_ * H_, cfin + (size_t)B_ * H_, L_, 0);
    // self-attn, last query
    attn0_mfma<<<B_, 256, 0, stream>>>(encout, wqkvh, bqkv, Wqkv, Wo, bo, a0last);
    // decoder
    lstm_mfma_kernel<<<256, 256, 0, stream>>>(
        target, a0last, wh2, dbih0, dbhh0, hfin, cfin,
        hseq1, nullptr, nullptr, T_, 1);
    lstm_mfma_kernel<<<256, 256, 0, stream>>>(
        hseq1, nullptr, wh3, dbih1, dbhh1,
        hfin + (size_t)B_ * H_, cfin + (size_t)B_ * H_, decout, nullptr, nullptr, T_, 0);
    // cross-attention + out-proj + FC (all-MFMA)
    (void)hipFuncSetAttribute((const void*)cross_attn_mfma,
                              hipFuncAttributeMaxDynamicSharedMemorySize, 73728);
    cross_attn_mfma<<<1024, 256, 73728, stream>>>(
        encout, decout, wqkvh, bqkv, woh, bo, w1h, b1, W2, b2, pred, attnw);
}

// Round 4
// 593.604 us; speedup vs baseline: 4.9361x; 1.7438x over previous
//
#include <hip/hip_runtime.h>
#include <hip/hip_bf16.h>
#include <cstddef>

// ---------------------------------------------------------------------------
// LSTMSeq2Seq: B=4096, L=64, T=48, H=64, NH=4, HD=16, NQ=3
// Round 4: S^T-orientation attention (no atomics, 4 blk/CU), 8-wave LSTM,
// barrier-free batched out-proj+FC kernel.
// ---------------------------------------------------------------------------

#define B_   4096
#define L_   64
#define T_   48
#define H_   64
#define ROWS 16
#define PADH 136     // LSTM A16 row pad (halves)
#define PADR 20      // LSTM gb col pad (floats)

using half8  = __attribute__((ext_vector_type(8))) _Float16;
using half4  = __attribute__((ext_vector_type(4))) _Float16;
using half2v = __attribute__((ext_vector_type(2))) _Float16;
using f32x4  = __attribute__((ext_vector_type(4))) float;
using f32x2  = __attribute__((ext_vector_type(2))) float;

__device__ __forceinline__ float sigf(float x) { return 1.0f / (1.0f + expf(-x)); }

#define IC_ 4.8828125e-4f   // 2^-11

// ---------------------------------------------------------------------------
// LSTM weight split (one-time): whalf[split][gate_row 256][k 128]
// ---------------------------------------------------------------------------
__global__ void transpose_w_kernel(const float* __restrict__ Wih,
                                   const float* __restrict__ Whh,
                                   _Float16* __restrict__ out) {
    int idx = blockIdx.x * 256 + threadIdx.x;
    if (idx >= 16384) return;
    int r = idx >> 6, k = idx & 63;
    float wi = Wih[idx];
    _Float16 hi = (_Float16)wi;
    out[r * 128 + k] = hi;
    out[32768 + r * 128 + k] = (_Float16)((wi - (float)hi) * 2048.0f);
    float wh = Whh[idx];
    hi = (_Float16)wh;
    out[r * 128 + 64 + k] = hi;
    out[32768 + r * 128 + 64 + k] = (_Float16)((wh - (float)hi) * 2048.0f);
}

// Attention weight splits: wqkvh[2][192][64], woh[2][64][64], w1h[2][32][64]
__global__ void split_aux_kernel(const float* __restrict__ Wqkv,
                                 const float* __restrict__ Wo,
                                 const float* __restrict__ W1,
                                 _Float16* __restrict__ wqkvh,
                                 _Float16* __restrict__ woh,
                                 _Float16* __restrict__ w1h) {
    int idx = blockIdx.x * 256 + threadIdx.x;
    if (idx < 12288) {
        float v = Wqkv[idx]; _Float16 h = (_Float16)v;
        wqkvh[idx] = h; wqkvh[12288 + idx] = (_Float16)((v - (float)h) * 2048.f);
    } else if (idx < 16384) {
        int i = idx - 12288;
        float v = Wo[i]; _Float16 h = (_Float16)v;
        woh[i] = h; woh[4096 + i] = (_Float16)((v - (float)h) * 2048.f);
    } else if (idx < 18432) {
        int i = idx - 16384;
        float v = W1[i]; _Float16 h = (_Float16)v;
        w1h[i] = h; w1h[2048 + i] = (_Float16)((v - (float)h) * 2048.f);
    }
}

// ---------------------------------------------------------------------------
// MFMA LSTM layer, 512 threads (8 waves): wave w owns gate cols [w*32,w*32+32).
// 256 blocks x 16 batch rows. fp16 hi/lo split GEMM, W resident in VGPRs.
// ---------------------------------------------------------------------------
__global__ __launch_bounds__(512, 2) void lstm_mfma_kernel(
    const float* __restrict__ inseq,
    const float* __restrict__ in0,
    const _Float16* __restrict__ whalf,   // [2][256][128]
    const float* __restrict__ bih,
    const float* __restrict__ bhh,
    const float* __restrict__ h0,
    const float* __restrict__ c0,
    float* __restrict__ outseq,
    float* __restrict__ hfin,
    float* __restrict__ cfin,
    int S, int mode)
{
    __shared__ __align__(16) _Float16 A16[2 * 16 * PADH];
    __shared__ __align__(16) float gb[256 * PADR];

    const int tid  = threadIdx.x;
    const int w    = tid >> 6;          // 0..7
    const int l    = tid & 63;
    const int lrow = l & 15;
    const int lkg  = l >> 4;
    const int row0 = blockIdx.x * ROWS;

    half8 whi[4][2], wlo[4][2];
    #pragma unroll
    for (int kt = 0; kt < 4; ++kt) {
        #pragma unroll
        for (int nt = 0; nt < 2; ++nt) {
            const int col = w * 32 + nt * 16 + lrow;
            const size_t off = (size_t)col * 128 + kt * 32 + lkg * 8;
            whi[kt][nt] = *(const half8*)&whalf[off];
            wlo[kt][nt] = *(const half8*)&whalf[32768 + off];
        }
    }
    float bsum[2];
    #pragma unroll
    for (int nt = 0; nt < 2; ++nt) {
        const int col = w * 32 + nt * 16 + lrow;
        bsum[nt] = bih[col] + bhh[col];
    }

    // staging map (x rows), cell-update map (2 rows per thread)
    const int rx = tid >> 5, kx = (tid & 31) * 2;
    const int ju = tid & 63, ru = (tid >> 6) * 2;

    // prologue: stage x(0) | h0, load c0
    {
        const float* p0 = (mode == 1) ? (in0 + (size_t)(row0 + rx) * 64)
                                      : (inseq + (size_t)(row0 + rx) * S * 64);
        f32x2 v = *(const f32x2*)(p0 + kx);
        half2v hi2, lo2;
        hi2[0] = (_Float16)v[0]; lo2[0] = (_Float16)((v[0] - (float)hi2[0]) * 2048.f);
        hi2[1] = (_Float16)v[1]; lo2[1] = (_Float16)((v[1] - (float)hi2[1]) * 2048.f);
        *(half2v*)&A16[rx * PADH + kx] = hi2;
        *(half2v*)&A16[16 * PADH + rx * PADH + kx] = lo2;
    }
    float c[2], hlast[2] = {0.f, 0.f};
    #pragma unroll
    for (int i = 0; i < 2; ++i) {
        float hv = h0 ? h0[(size_t)(row0 + ru + i) * 64 + ju] : 0.f;
        _Float16 hh = (_Float16)hv;
        A16[(ru + i) * PADH + 64 + ju] = hh;
        A16[16 * PADH + (ru + i) * PADH + 64 + ju] =
            (_Float16)((hv - (float)hh) * 2048.f);
        c[i] = c0 ? c0[(size_t)(row0 + ru + i) * 64 + ju] : 0.f;
    }

    const int aoffh = lrow * PADH + lkg * 8;

    for (int t = 0; t < S; ++t) {
        __syncthreads();   // A16 ready

        f32x2 xn;
        if (t + 1 < S) {
            const float* pn = (mode == 1)
                ? (inseq + ((size_t)(row0 + rx) * S + t) * 64)
                : (inseq + ((size_t)(row0 + rx) * S + (t + 1)) * 64);
            xn = *(const f32x2*)(pn + kx);
        }

        f32x4 acc0[2], acc1[2];
        #pragma unroll
        for (int nt = 0; nt < 2; ++nt) {
            acc0[nt] = (f32x4){bsum[nt], bsum[nt], bsum[nt], bsum[nt]};
            acc1[nt] = (f32x4){0.f, 0.f, 0.f, 0.f};
        }
        #pragma unroll
        for (int kt = 0; kt < 4; ++kt) {
            half8 ah = *(const half8*)&A16[aoffh + kt * 32];
            half8 al = *(const half8*)&A16[16 * PADH + aoffh + kt * 32];
            #pragma unroll
            for (int nt = 0; nt < 2; ++nt)
                acc0[nt] = __builtin_amdgcn_mfma_f32_16x16x32_f16(ah, whi[kt][nt], acc0[nt], 0, 0, 0);
            #pragma unroll
            for (int nt = 0; nt < 2; ++nt)
                acc1[nt] = __builtin_amdgcn_mfma_f32_16x16x32_f16(ah, wlo[kt][nt], acc1[nt], 0, 0, 0);
            #pragma unroll
            for (int nt = 0; nt < 2; ++nt)
                acc1[nt] = __builtin_amdgcn_mfma_f32_16x16x32_f16(al, whi[kt][nt], acc1[nt], 0, 0, 0);
        }
        #pragma unroll
        for (int nt = 0; nt < 2; ++nt) {
            f32x4 g = acc0[nt] + acc1[nt] * IC_;
            const int col = w * 32 + nt * 16 + lrow;
            *(f32x4*)&gb[col * PADR + lkg * 4] = g;
        }
        __syncthreads();   // gb ready; A16 reads drained

        {
            f32x2 gi = *(const f32x2*)&gb[(0 * 64 + ju) * PADR + ru];
            f32x2 gf = *(const f32x2*)&gb[(1 * 64 + ju) * PADR + ru];
            f32x2 gg = *(const f32x2*)&gb[(2 * 64 + ju) * PADR + ru];
            f32x2 go = *(const f32x2*)&gb[(3 * 64 + ju) * PADR + ru];
            #pragma unroll
            for (int i = 0; i < 2; ++i) {
                c[i] = sigf(gf[i]) * c[i] + sigf(gi[i]) * tanhf(gg[i]);
                float hv = sigf(go[i]) * tanhf(c[i]);
                hlast[i] = hv;
                outseq[((size_t)(row0 + ru + i) * S + t) * 64 + ju] = hv;
                _Float16 hh = (_Float16)hv;
                A16[(ru + i) * PADH + 64 + ju] = hh;
                A16[16 * PADH + (ru + i) * PADH + 64 + ju] =
                    (_Float16)((hv - (float)hh) * 2048.f);
            }
        }
        if (t + 1 < S) {
            half2v hi2, lo2;
            hi2[0] = (_Float16)xn[0]; lo2[0] = (_Float16)((xn[0] - (float)hi2[0]) * 2048.f);
            hi2[1] = (_Float16)xn[1]; lo2[1] = (_Float16)((xn[1] - (float)hi2[1]) * 2048.f);
            *(half2v*)&A16[rx * PADH + kx] = hi2;
            *(half2v*)&A16[16 * PADH + rx * PADH + kx] = lo2;
        }
    }
    if (hfin) {
        #pragma unroll
        for (int i = 0; i < 2; ++i) {
            hfin[(size_t)(row0 + ru + i) * 64 + ju] = hlast[i];
            cfin[(size_t)(row0 + ru + i) * 64 + ju] = c[i];
        }
    }
}

// ---------------------------------------------------------------------------
// Helper: stage a fp32 row-block into hi/lo fp16 LDS planes [R][72] (attn0)
// ---------------------------------------------------------------------------
__device__ __forceinline__ void stage_split(const float* __restrict__ src,
                                            _Float16* dst, int plane,
                                            int row, int c0) {
    #pragma unroll
    for (int u = 0; u < 4; ++u) {
        float4 v = *(const float4*)(src + u * 4);
        half4 hi, lo;
        hi[0] = (_Float16)v.x; lo[0] = (_Float16)((v.x - (float)hi[0]) * 2048.f);
        hi[1] = (_Float16)v.y; lo[1] = (_Float16)((v.y - (float)hi[1]) * 2048.f);
        hi[2] = (_Float16)v.z; lo[2] = (_Float16)((v.z - (float)hi[2]) * 2048.f);
        hi[3] = (_Float16)v.w; lo[3] = (_Float16)((v.w - (float)hi[3]) * 2048.f);
        *(half4*)&dst[row * 72 + c0 + u * 4] = hi;
        *(half4*)&dst[plane + row * 72 + c0 + u * 4] = lo;
    }
}

// ---------------------------------------------------------------------------
// Self-attention, last query only (unchanged from round 3, known-good).
// ---------------------------------------------------------------------------
__global__ __launch_bounds__(256) void attn0_mfma(
    const float* __restrict__ encout,
    const _Float16* __restrict__ wqkvh,
    const float* __restrict__ bqkv,
    const float* __restrict__ Wqkv,
    const float* __restrict__ Wo,
    const float* __restrict__ bo,
    float* __restrict__ a0last)
{
    __shared__ __align__(16) _Float16 E16[2 * 4608];
    __shared__ __align__(16) _Float16 K16[2 * 4608];
    __shared__ __align__(16) _Float16 V16[4608];
    __shared__ float qv[64];
    __shared__ float wrow[4 * 68];
    __shared__ float ov[64];

    const int b = blockIdx.x, tid = threadIdx.x;
    const int w = tid >> 6, l = tid & 63, lr = l & 15, lkg = l >> 4;

    {
        int row = tid >> 2, c0 = (tid & 3) * 16;
        stage_split(encout + (size_t)b * 4096 + row * 64 + c0, E16, 4608, row, c0);
    }
    __syncthreads();

    for (int tt = w; tt < 8; tt += 4) {
        const int kind = (tt < 4) ? 0 : 1;
        const int mrow = (kind ? tt - 4 : tt) * 16;
        const int wrowB = kind ? 128 : 64;
        half8 ah[2], al[2];
        #pragma unroll
        for (int kt = 0; kt < 2; ++kt) {
            int ao = (mrow + lr) * 72 + kt * 32 + lkg * 8;
            ah[kt] = *(const half8*)&E16[ao];
            al[kt] = *(const half8*)&E16[4608 + ao];
        }
        #pragma unroll
        for (int nt = 0; nt < 4; ++nt) {
            const int col = nt * 16 + lr;
            const float bv = bqkv[wrowB + col];
            f32x4 a0 = (f32x4){bv, bv, bv, bv};
            f32x4 a1 = (f32x4){0.f, 0.f, 0.f, 0.f};
            #pragma unroll
            for (int kt = 0; kt < 2; ++kt) {
                const _Float16* wp = wqkvh + (size_t)(wrowB + col) * 64 + kt * 32 + lkg * 8;
                half8 bh = *(const half8*)wp;
                half8 bl = *(const half8*)(wp + 12288);
                a0 = __builtin_amdgcn_mfma_f32_16x16x32_f16(ah[kt], bh, a0, 0, 0, 0);
                a1 = __builtin_amdgcn_mfma_f32_16x16x32_f16(ah[kt], bl, a1, 0, 0, 0);
                a1 = __builtin_amdgcn_mfma_f32_16x16x32_f16(al[kt], bh, a1, 0, 0, 0);
            }
            #pragma unroll
            for (int i = 0; i < 4; ++i) {
                float g = a0[i] + a1[i] * IC_;
                int r = mrow + lkg * 4 + i;
                if (kind == 0) {
                    _Float16 gh = (_Float16)g;
                    K16[r * 72 + col] = gh;
                    K16[4608 + r * 72 + col] = (_Float16)((g - (float)gh) * 2048.f);
                } else {
                    V16[r * 72 + col] = (_Float16)g;
                }
            }
        }
    }
    if (w == 3) {
        float a = bqkv[l];
        for (int k = 0; k < 64; ++k) {
            float e = (float)E16[63 * 72 + k] + (float)E16[4608 + 63 * 72 + k] * IC_;
            a += e * Wqkv[l * 64 + k];
        }
        qv[l] = a;
    }
    __syncthreads();

    {
        const int h = tid >> 6, kv = tid & 63;
        float s = 0.f;
        #pragma unroll
        for (int d = 0; d < 16; ++d) {
            float kk = (float)K16[kv * 72 + h * 16 + d]
                     + (float)K16[4608 + kv * 72 + h * 16 + d] * IC_;
            s += qv[h * 16 + d] * kk;
        }
        s *= 0.25f;
        float m = s;
        #pragma unroll
        for (int off = 32; off; off >>= 1) m = fmaxf(m, __shfl_xor(m, off));
        float e = expf(s - m);
        float sum = e;
        #pragma unroll
        for (int off = 32; off; off >>= 1) sum += __shfl_xor(sum, off);
        wrow[h * 68 + kv] = e / sum;
    }
    __syncthreads();
    if (tid < 64) {
        const int h = tid >> 4, d = tid & 15;
        float o = 0.f;
        for (int kv = 0; kv < 64; ++kv)
            o += wrow[h * 68 + kv] * (float)V16[kv * 72 + h * 16 + d];
        ov[tid] = o;
    }
    __syncthreads();
    if (tid < 64) {
        float a = bo[tid];
        for (int k = 0; k < 64; ++k) a += ov[k] * Wo[tid * 64 + k];
        a0last[(size_t)b * 64 + tid] = a;
    }
}

// ---------------------------------------------------------------------------
// Cross-attention v2: one b per block, S^T scores, no atomics, 4 barriers.
// Dynamic LDS 40960 B -> 4 blocks/CU. Writes attnw (fp32) and AO (fp16).
// Regions: E[64][72]@0, D[48][72]@9216, K[64][72]@16128, Q[48][72]@25344,
//          VT[64][68]@32256. w-strips (fp16 [48][72] per head) alias E/D/K/Q.
// ---------------------------------------------------------------------------
__global__ __launch_bounds__(256, 4) void cross_attn_v2(
    const float* __restrict__ encout, const float* __restrict__ decout,
    const _Float16* __restrict__ wqkvh, const float* __restrict__ bqkv,
    _Float16* __restrict__ AOg, float* __restrict__ attnw)
{
    extern __shared__ __align__(16) char smem[];
    _Float16* E  = (_Float16*)(smem);
    _Float16* D  = (_Float16*)(smem + 9216);
    _Float16* K  = (_Float16*)(smem + 16128);
    _Float16* Q  = (_Float16*)(smem + 25344);
    _Float16* VT = (_Float16*)(smem + 32256);

    const int b = blockIdx.x, tid = threadIdx.x;
    const int w = tid >> 6, l = tid & 63, lr = l & 15, lkg = l >> 4;
    const int h = w;   // wave = head

    // ---- P0: stage E, D (single fp16) --------------------------------------
    {
        int row = tid >> 2, c0 = (tid & 3) * 16;
        const float* ep = encout + (size_t)b * 4096 + row * 64 + c0;
        half8 v0, v1;
        #pragma unroll
        for (int j = 0; j < 8; ++j) v0[j] = (_Float16)ep[j];
        #pragma unroll
        for (int j = 0; j < 8; ++j) v1[j] = (_Float16)ep[8 + j];
        *(half8*)&E[row * 72 + c0] = v0;
        *(half8*)&E[row * 72 + c0 + 8] = v1;
        if (row < 48) {
            const float* dp = decout + (size_t)b * 3072 + row * 64 + c0;
            half8 u0, u1;
            #pragma unroll
            for (int j = 0; j < 8; ++j) u0[j] = (_Float16)dp[j];
            #pragma unroll
            for (int j = 0; j < 8; ++j) u1[j] = (_Float16)dp[8 + j];
            *(half8*)&D[row * 72 + c0] = u0;
            *(half8*)&D[row * 72 + c0 + 8] = u1;
        }
    }
    __syncthreads();   // b1

    // ---- P1: K/V/Q projections (11 tiles over 4 waves, hi-weights only) ----
    for (int tt = w; tt < 11; tt += 4) {
        const int kind = (tt < 4) ? 0 : ((tt < 8) ? 1 : 2);
        const int mrow = ((kind == 0) ? tt : (kind == 1) ? tt - 4 : tt - 8) * 16;
        const int wrowB = (kind == 0) ? 64 : ((kind == 1) ? 128 : 0);
        const _Float16* S = (kind == 2) ? D : E;
        half8 ah[2];
        #pragma unroll
        for (int kt = 0; kt < 2; ++kt)
            ah[kt] = *(const half8*)&S[(mrow + lr) * 72 + kt * 32 + lkg * 8];
        #pragma unroll
        for (int nt = 0; nt < 4; ++nt) {
            const int col = nt * 16 + lr;
            const float bv = bqkv[wrowB + col];
            f32x4 a0 = (f32x4){bv, bv, bv, bv};
            #pragma unroll
            for (int kt = 0; kt < 2; ++kt) {
                half8 bh = *(const half8*)&wqkvh[(size_t)(wrowB + col) * 64 + kt * 32 + lkg * 8];
                a0 = __builtin_amdgcn_mfma_f32_16x16x32_f16(ah[kt], bh, a0, 0, 0, 0);
            }
            if (kind == 1) {          // V -> transposed VT[d][kv]
                half4 p;
                #pragma unroll
                for (int i = 0; i < 4; ++i) p[i] = (_Float16)a0[i];
                *(half4*)&VT[col * 68 + mrow + lkg * 4] = p;
            } else {
                _Float16* dst = (kind == 0) ? K : Q;
                #pragma unroll
                for (int i = 0; i < 4; ++i)
                    dst[(mrow + lkg * 4 + i) * 72 + col] = (_Float16)a0[i];
            }
        }
    }
    __syncthreads();   // b2

    // ---- P2a: score fragments (zero-padded K=32, per-head d=16) ------------
    const half8 z = {0, 0, 0, 0, 0, 0, 0, 0};
    half8 ka[4], qb[3];
    #pragma unroll
    for (int kvt = 0; kvt < 4; ++kvt)
        ka[kvt] = (lkg < 2) ? *(const half8*)&K[(kvt * 16 + lr) * 72 + h * 16 + lkg * 8] : z;
    #pragma unroll
    for (int qt = 0; qt < 3; ++qt)
        qb[qt] = (lkg < 2) ? *(const half8*)&Q[(qt * 16 + lr) * 72 + h * 16 + lkg * 8] : z;
    __syncthreads();   // b3: K/Q/E/D now dead -> strips may overwrite

    // ---- P2b: S^T = K·Q^T, softmax, strips, PV, AO stores ------------------
    _Float16* strip = (_Float16*)(smem + ((h == 0) ? 0 : (h == 1) ? 9216
                                        : (h == 2) ? 16128 : 25344));
    {
        f32x4 s[3][4];
        #pragma unroll
        for (int qt = 0; qt < 3; ++qt) {
            #pragma unroll
            for (int kvt = 0; kvt < 4; ++kvt) {
                f32x4 a0 = (f32x4){0.f, 0.f, 0.f, 0.f};
                a0 = __builtin_amdgcn_mfma_f32_16x16x32_f16(ka[kvt], qb[qt], a0, 0, 0, 0);
                s[qt][kvt] = a0 * 0.25f;
            }
            // softmax over kv = (kvt, i, lkg)
            float m = s[qt][0][0];
            #pragma unroll
            for (int kvt = 0; kvt < 4; ++kvt)
                #pragma unroll
                for (int i = 0; i < 4; ++i) m = fmaxf(m, s[qt][kvt][i]);
            m = fmaxf(m, __shfl_xor(m, 16));
            m = fmaxf(m, __shfl_xor(m, 32));
            float sum = 0.f;
            #pragma unroll
            for (int kvt = 0; kvt < 4; ++kvt)
                #pragma unroll
                for (int i = 0; i < 4; ++i) {
                    float e = expf(s[qt][kvt][i] - m);
                    s[qt][kvt][i] = e;
                    sum += e;
                }
            sum += __shfl_xor(sum, 16);
            sum += __shfl_xor(sum, 32);
            const float r = 1.0f / sum;
            #pragma unroll
            for (int kvt = 0; kvt < 4; ++kvt) {
                half4 p;
                #pragma unroll
                for (int i = 0; i < 4; ++i) p[i] = (_Float16)(s[qt][kvt][i] * r);
                *(half4*)&strip[(qt * 16 + lr) * 72 + kvt * 16 + lkg * 4] = p;
            }
        }
    }
    // PV: A from own strip (same-wave LDS, in-order), B from VT
    {
        half8 vb[2];
        #pragma unroll
        for (int kt = 0; kt < 2; ++kt) {
            half4 lo4 = *(const half4*)&VT[(h * 16 + lr) * 68 + kt * 32 + lkg * 8];
            half4 hi4 = *(const half4*)&VT[(h * 16 + lr) * 68 + kt * 32 + lkg * 8 + 4];
            #pragma unroll
            for (int j = 0; j < 4; ++j) { vb[kt][j] = lo4[j]; vb[kt][4 + j] = hi4[j]; }
        }
        #pragma unroll
        for (int qt = 0; qt < 3; ++qt) {
            f32x4 acc = (f32x4){0.f, 0.f, 0.f, 0.f};
            #pragma unroll
            for (int kt = 0; kt < 2; ++kt) {
                half8 wa = *(const half8*)&strip[(qt * 16 + lr) * 72 + kt * 32 + lkg * 8];
                acc = __builtin_amdgcn_mfma_f32_16x16x32_f16(wa, vb[kt], acc, 0, 0, 0);
            }
            #pragma unroll
            for (int i = 0; i < 4; ++i)
                AOg[((size_t)b * 48 + qt * 16 + lkg * 4 + i) * 64 + h * 16 + lr] =
                    (_Float16)acc[i];
        }
    }
    __syncthreads();   // b4: all strips ready

    // ---- P3: attnw = head-mean of strips -----------------------------------
    {
        const _Float16* s0 = (const _Float16*)(smem);
        const _Float16* s1 = (const _Float16*)(smem + 9216);
        const _Float16* s2 = (const _Float16*)(smem + 16128);
        const _Float16* s3 = (const _Float16*)(smem + 25344);
        #pragma unroll
        for (int it = 0; it < 12; ++it) {
            int idx = tid + it * 256;
            int o = (idx >> 6) * 72 + (idx & 63);
            attnw[(size_t)b * 3072 + idx] =
                0.25f * ((float)s0[o] + (float)s1[o] + (float)s2[o] + (float)s3[o]);
        }
    }
}

// ---------------------------------------------------------------------------
// Batched out-proj + FC1(relu) + FC2. 64 rows/block, zero barriers.
// ---------------------------------------------------------------------------
__global__ __launch_bounds__(256) void proj_fc_kernel(
    const _Float16* __restrict__ AOg,
    const _Float16* __restrict__ woh, const float* __restrict__ bo,
    const _Float16* __restrict__ w1h, const float* __restrict__ b1,
    const float* __restrict__ W2,     const float* __restrict__ b2,
    float* __restrict__ pred)
{
    __shared__ __align__(16) _Float16 obuf[4][16 * 72];
    __shared__ float h1buf[4][16 * 36];
    const int tid = threadIdx.x;
    const int w = tid >> 6, l = tid & 63, lr = l & 15, lkg = l >> 4;
    const size_t r0 = (size_t)blockIdx.x * 64 + w * 16;

    // out-proj: A = AO rows (global), B = woh (hi)
    half8 ah[2];
    #pragma unroll
    for (int kt = 0; kt < 2; ++kt)
        ah[kt] = *(const half8*)&AOg[(r0 + lr) * 64 + kt * 32 + lkg * 8];
    #pragma unroll
    for (int nt = 0; nt < 4; ++nt) {
        const int col = nt * 16 + lr;
        const float bv = bo[col];
        f32x4 a0 = (f32x4){bv, bv, bv, bv};
        #pragma unroll
        for (int kt = 0; kt < 2; ++kt) {
            half8 bh = *(const half8*)&woh[(size_t)col * 64 + kt * 32 + lkg * 8];
            a0 = __builtin_amdgcn_mfma_f32_16x16x32_f16(ah[kt], bh, a0, 0, 0, 0);
        }
        #pragma unroll
        for (int i = 0; i < 4; ++i)
            obuf[w][(lkg * 4 + i) * 72 + col] = (_Float16)a0[i];
    }
    // FC1 (same-wave LDS RAW: in-order)
    half8 oh[2];
    #pragma unroll
    for (int kt = 0; kt < 2; ++kt)
        oh[kt] = *(const half8*)&obuf[w][lr * 72 + kt * 32 + lkg * 8];
    #pragma unroll
    for (int nt = 0; nt < 2; ++nt) {
        const int m = nt * 16 + lr;
        const float bv = b1[m];
        f32x4 a0 = (f32x4){bv, bv, bv, bv};
        #pragma unroll
        for (int kt = 0; kt < 2; ++kt) {
            half8 bh = *(const half8*)&w1h[(size_t)m * 64 + kt * 32 + lkg * 8];
            a0 = __builtin_amdgcn_mfma_f32_16x16x32_f16(oh[kt], bh, a0, 0, 0, 0);
        }
        #pragma unroll
        for (int i = 0; i < 4; ++i)
            h1buf[w][(lkg * 4 + i) * 36 + m] = fmaxf(a0[i], 0.f);
    }
    // FC2 (same-wave)
    if (l < 48) {
        const int q = l / 3, n = l - 3 * q;
        float a = b2[n];
        #pragma unroll
        for (int m2 = 0; m2 < 32; ++m2)
            a += h1buf[w][q * 36 + m2] * W2[n * 32 + m2];
        pred[(r0 + q) * 3 + n] = a;
    }
}

// ---------------------------------------------------------------------------
extern "C" void kernel_launch(void* const* d_in, const int* in_sizes, int n_in,
                              void* d_out, int out_size, void* d_ws, size_t ws_size,
                              hipStream_t stream) {
    const float* x      = (const float*)d_in[0];
    const float* target = (const float*)d_in[1];
    const float* eWih0 = (const float*)d_in[2],  *eWhh0 = (const float*)d_in[3];
    const float* ebih0 = (const float*)d_in[4],  *ebhh0 = (const float*)d_in[5];
    const float* eWih1 = (const float*)d_in[6],  *eWhh1 = (const float*)d_in[7];
    const float* ebih1 = (const float*)d_in[8],  *ebhh1 = (const float*)d_in[9];
    const float* dWih0 = (const float*)d_in[10], *dWhh0 = (const float*)d_in[11];
    const float* dbih0 = (const float*)d_in[12], *dbhh0 = (const float*)d_in[13];
    const float* dWih1 = (const float*)d_in[14], *dWhh1 = (const float*)d_in[15];
    const float* dbih1 = (const float*)d_in[16], *dbhh1 = (const float*)d_in[17];
    const float* Wqkv = (const float*)d_in[18], *bqkv = (const float*)d_in[19];
    const float* Wo   = (const float*)d_in[20], *bo   = (const float*)d_in[21];
    const float* W1   = (const float*)d_in[22], *b1   = (const float*)d_in[23];
    const float* W2   = (const float*)d_in[24], *b2   = (const float*)d_in[25];

    float* ws = (float*)d_ws;
    float* hseq1  = ws;                                   // B*L*64 (also AOg later)
    float* encout = hseq1  + (size_t)B_ * L_ * H_;
    float* decout = encout + (size_t)B_ * L_ * H_;
    float* a0last = decout + (size_t)B_ * T_ * H_;
    float* hfin   = a0last + (size_t)B_ * H_;
    float* cfin   = hfin   + (size_t)2 * B_ * H_;
    float* wtg    = cfin   + (size_t)2 * B_ * H_;
    float* auxw   = wtg    + (size_t)4 * 32768;

    _Float16* wh0 = (_Float16*)(wtg);
    _Float16* wh1 = wh0 + 65536;
    _Float16* wh2 = wh1 + 65536;
    _Float16* wh3 = wh2 + 65536;
    _Float16* wqkvh = (_Float16*)auxw;        // [2][192][64]
    _Float16* woh   = wqkvh + 24576;          // [2][64][64]
    _Float16* w1h   = woh + 8192;             // [2][32][64]
    _Float16* AOg   = (_Float16*)hseq1;       // aliases hseq1 (dead after dec L2)

    float* pred  = (float*)d_out;
    float* attnw = pred + (size_t)B_ * T_ * 3;

    transpose_w_kernel<<<64, 256, 0, stream>>>(eWih0, eWhh0, wh0);
    transpose_w_kernel<<<64, 256, 0, stream>>>(eWih1, eWhh1, wh1);
    transpose_w_kernel<<<64, 256, 0, stream>>>(dWih0, dWhh0, wh2);
    transpose_w_kernel<<<64, 256, 0, stream>>>(dWih1, dWhh1, wh3);
    split_aux_kernel<<<72, 256, 0, stream>>>(Wqkv, Wo, W1, wqkvh, woh, w1h);

    // encoder
    lstm_mfma_kernel<<<256, 512, 0, stream>>>(
        x, nullptr, wh0, ebih0, ebhh0, nullptr, nullptr,
        hseq1, hfin, cfin, L_, 0);
    lstm_mfma_kernel<<<256, 512, 0, stream>>>(
        hseq1, nullptr, wh1, ebih1, ebhh1, nullptr, nullptr,
        encout, hfin + (size_t)B_ * H_, cfin + (size_t)B_ * H_, L_, 0);
    // self-attn, last query
    attn0_mfma<<<B_, 256, 0, stream>>>(encout, wqkvh, bqkv, Wqkv, Wo, bo, a0last);
    // decoder
    lstm_mfma_kernel<<<256, 512, 0, stream>>>(
        target, a0last, wh2, dbih0, dbhh0, hfin, cfin,
        hseq1, nullptr, nullptr, T_, 1);
    lstm_mfma_kernel<<<256, 512, 0, stream>>>(
        hseq1, nullptr, wh3, dbih1, dbhh1,
        hfin + (size_t)B_ * H_, cfin + (size_t)B_ * H_, decout, nullptr, nullptr, T_, 0);
    // cross-attention (scores/softmax/PV/attnw) -> AOg, attnw
    cross_attn_v2<<<B_, 256, 40960, stream>>>(
        encout, decout, wqkvh, bqkv, AOg, attnw);
    // out-proj + FC1 + FC2 -> pred
    proj_fc_kernel<<<(B_ * T_) / 64, 256, 0, stream>>>(
        AOg, woh, bo, w1h, b1, W2, b2, pred);
}

// Round 5
// 429.479 us; speedup vs baseline: 6.8225x; 1.3821x over previous
//
#include <hip/hip_runtime.h>
#include <hip/hip_bf16.h>
#include <cstddef>

// ---------------------------------------------------------------------------
// LSTMSeq2Seq: B=4096, L=64, T=48, H=64, NH=4, HD=16, NQ=3
// Round 5: fused 2-layer LSTM (skewed pipeline, 2 barriers/step for BOTH
// layers), native-rate sigmoid/tanh, PADR=18 bank fix.
// ---------------------------------------------------------------------------

#define B_   4096
#define L_   64
#define T_   48
#define H_   64
#define ROWS 16
#define PADH 136     // LSTM A row pad (halves)
#define PADR 18      // LSTM gb col pad (floats; 18 ≡ full bank coverage)

using half8  = __attribute__((ext_vector_type(8))) _Float16;
using half4  = __attribute__((ext_vector_type(4))) _Float16;
using half2v = __attribute__((ext_vector_type(2))) _Float16;
using f32x4  = __attribute__((ext_vector_type(4))) float;
using f32x2  = __attribute__((ext_vector_type(2))) float;

#define IC_ 4.8828125e-4f   // 2^-11

// native-rate transcendentals (v_exp_f32 + v_rcp_f32); overflow-safe forms
__device__ __forceinline__ float fsig(float x) {
    return __builtin_amdgcn_rcpf(1.0f + __expf(-x));
}
__device__ __forceinline__ float ftanh(float x) {
    float e = __expf(-2.0f * fabsf(x));            // e in (0,1], never overflows
    float r = (1.0f - e) * __builtin_amdgcn_rcpf(1.0f + e);
    return copysignf(r, x);
}

// ---------------------------------------------------------------------------
// LSTM weight split (one-time): whalf[split][gate_row 256][k 128]
// ---------------------------------------------------------------------------
__global__ void transpose_w_kernel(const float* __restrict__ Wih,
                                   const float* __restrict__ Whh,
                                   _Float16* __restrict__ out) {
    int idx = blockIdx.x * 256 + threadIdx.x;
    if (idx >= 16384) return;
    int r = idx >> 6, k = idx & 63;
    float wi = Wih[idx];
    _Float16 hi = (_Float16)wi;
    out[r * 128 + k] = hi;
    out[32768 + r * 128 + k] = (_Float16)((wi - (float)hi) * 2048.0f);
    float wh = Whh[idx];
    hi = (_Float16)wh;
    out[r * 128 + 64 + k] = hi;
    out[32768 + r * 128 + 64 + k] = (_Float16)((wh - (float)hi) * 2048.0f);
}

// Attention weight splits: wqkvh[2][192][64], woh[2][64][64], w1h[2][32][64]
__global__ void split_aux_kernel(const float* __restrict__ Wqkv,
                                 const float* __restrict__ Wo,
                                 const float* __restrict__ W1,
                                 _Float16* __restrict__ wqkvh,
                                 _Float16* __restrict__ woh,
                                 _Float16* __restrict__ w1h) {
    int idx = blockIdx.x * 256 + threadIdx.x;
    if (idx < 12288) {
        float v = Wqkv[idx]; _Float16 h = (_Float16)v;
        wqkvh[idx] = h; wqkvh[12288 + idx] = (_Float16)((v - (float)h) * 2048.f);
    } else if (idx < 16384) {
        int i = idx - 12288;
        float v = Wo[i]; _Float16 h = (_Float16)v;
        woh[i] = h; woh[4096 + i] = (_Float16)((v - (float)h) * 2048.f);
    } else if (idx < 18432) {
        int i = idx - 16384;
        float v = W1[i]; _Float16 h = (_Float16)v;
        w1h[i] = h; w1h[2048 + i] = (_Float16)((v - (float)h) * 2048.f);
    }
}

// ---------------------------------------------------------------------------
// Fused 2-layer LSTM, skewed: iteration i does L1 step i and L2 step i-1.
// 256 blocks x 512 threads; block owns 16 batch rows; wave w owns gate cols
// [w*32,(w+1)*32) of BOTH layers. W fragments resident in VGPRs (~128).
// 2 barriers per iteration for both layers.
// ---------------------------------------------------------------------------
__global__ __launch_bounds__(512, 1) void lstm2_mfma_kernel(
    const float* __restrict__ inseq,
    const float* __restrict__ in0,
    const _Float16* __restrict__ w1half,
    const float* __restrict__ b1ihp, const float* __restrict__ b1hhp,
    const _Float16* __restrict__ w2half,
    const float* __restrict__ b2ihp, const float* __restrict__ b2hhp,
    const float* __restrict__ h01, const float* __restrict__ c01,
    const float* __restrict__ h02, const float* __restrict__ c02,
    float* __restrict__ outseq2,
    float* __restrict__ hf1, float* __restrict__ cf1,
    float* __restrict__ hf2, float* __restrict__ cf2,
    int S, int mode)
{
    __shared__ __align__(16) _Float16 A1[2 * 16 * PADH];   // [plane][row][k]
    __shared__ __align__(16) _Float16 A2[2 * 16 * PADH];
    __shared__ __align__(16) float gb1[256 * PADR];
    __shared__ __align__(16) float gb2[256 * PADR];

    const int tid  = threadIdx.x;
    const int w    = tid >> 6;
    const int l    = tid & 63;
    const int lrow = l & 15;
    const int lkg  = l >> 4;
    const int row0 = blockIdx.x * ROWS;

    half8 w1hi[4][2], w1lo[4][2], w2hi[4][2], w2lo[4][2];
    #pragma unroll
    for (int kt = 0; kt < 4; ++kt)
        #pragma unroll
        for (int nt = 0; nt < 2; ++nt) {
            const int col = w * 32 + nt * 16 + lrow;
            const size_t off = (size_t)col * 128 + kt * 32 + lkg * 8;
            w1hi[kt][nt] = *(const half8*)&w1half[off];
            w1lo[kt][nt] = *(const half8*)&w1half[32768 + off];
            w2hi[kt][nt] = *(const half8*)&w2half[off];
            w2lo[kt][nt] = *(const half8*)&w2half[32768 + off];
        }
    float bs1[2], bs2[2];
    #pragma unroll
    for (int nt = 0; nt < 2; ++nt) {
        const int col = w * 32 + nt * 16 + lrow;
        bs1[nt] = b1ihp[col] + b1hhp[col];
        bs2[nt] = b2ihp[col] + b2hhp[col];
    }

    const int rx = tid >> 5, kx = (tid & 31) * 2;   // x staging map
    const int ju = tid & 63, ru = (tid >> 6) * 2;   // cell map: col ju, rows ru..ru+1

    // ---- prologue: A1 = [x(0) | h01], A2 h-part = h02, c's ----------------
    {
        const float* p0 = (mode == 1) ? (in0 + (size_t)(row0 + rx) * 64)
                                      : (inseq + (size_t)(row0 + rx) * S * 64);
        f32x2 v = *(const f32x2*)(p0 + kx);
        half2v hi2, lo2;
        hi2[0] = (_Float16)v[0]; lo2[0] = (_Float16)((v[0] - (float)hi2[0]) * 2048.f);
        hi2[1] = (_Float16)v[1]; lo2[1] = (_Float16)((v[1] - (float)hi2[1]) * 2048.f);
        *(half2v*)&A1[rx * PADH + kx] = hi2;
        *(half2v*)&A1[16 * PADH + rx * PADH + kx] = lo2;
    }
    float c1[2], c2[2], h1l[2] = {0.f, 0.f}, h2l[2] = {0.f, 0.f};
    #pragma unroll
    for (int r = 0; r < 2; ++r) {
        const int row = ru + r;
        float hv1 = h01 ? h01[(size_t)(row0 + row) * 64 + ju] : 0.f;
        _Float16 hh = (_Float16)hv1;
        A1[row * PADH + 64 + ju] = hh;
        A1[16 * PADH + row * PADH + 64 + ju] = (_Float16)((hv1 - (float)hh) * 2048.f);
        c1[r] = c01 ? c01[(size_t)(row0 + row) * 64 + ju] : 0.f;
        float hv2 = h02 ? h02[(size_t)(row0 + row) * 64 + ju] : 0.f;
        hh = (_Float16)hv2;
        A2[row * PADH + 64 + ju] = hh;
        A2[16 * PADH + row * PADH + 64 + ju] = (_Float16)((hv2 - (float)hh) * 2048.f);
        c2[r] = c02 ? c02[(size_t)(row0 + row) * 64 + ju] : 0.f;
    }

    const int aoff = lrow * PADH + lkg * 8;

    for (int i = 0; i <= S; ++i) {
        __syncthreads();   // A1/A2 (and gb consumers of prev iter) ready
        const bool doL1 = (i < S), doL2 = (i > 0);

        // prefetch x(i+1) early; drained at next barrier under the GEMM phase
        f32x2 xn;
        if (i + 1 < S) {
            const float* pn = (mode == 1)
                ? (inseq + ((size_t)(row0 + rx) * S + i) * 64)        // target[i]
                : (inseq + ((size_t)(row0 + rx) * S + (i + 1)) * 64);
            xn = *(const f32x2*)(pn + kx);
        }

        if (doL1) {   // GEMM1: gates1 = A1 @ W1^T
            f32x4 a0[2], a1[2];
            #pragma unroll
            for (int nt = 0; nt < 2; ++nt) {
                a0[nt] = (f32x4){bs1[nt], bs1[nt], bs1[nt], bs1[nt]};
                a1[nt] = (f32x4){0.f, 0.f, 0.f, 0.f};
            }
            #pragma unroll
            for (int kt = 0; kt < 4; ++kt) {
                half8 ah = *(const half8*)&A1[aoff + kt * 32];
                half8 al = *(const half8*)&A1[16 * PADH + aoff + kt * 32];
                #pragma unroll
                for (int nt = 0; nt < 2; ++nt) {
                    a0[nt] = __builtin_amdgcn_mfma_f32_16x16x32_f16(ah, w1hi[kt][nt], a0[nt], 0, 0, 0);
                    a1[nt] = __builtin_amdgcn_mfma_f32_16x16x32_f16(ah, w1lo[kt][nt], a1[nt], 0, 0, 0);
                    a1[nt] = __builtin_amdgcn_mfma_f32_16x16x32_f16(al, w1hi[kt][nt], a1[nt], 0, 0, 0);
                }
            }
            #pragma unroll
            for (int nt = 0; nt < 2; ++nt) {
                f32x4 g = a0[nt] + a1[nt] * IC_;
                const int col = w * 32 + nt * 16 + lrow;
                *(f32x2*)&gb1[col * PADR + lkg * 4]     = (f32x2){g[0], g[1]};
                *(f32x2*)&gb1[col * PADR + lkg * 4 + 2] = (f32x2){g[2], g[3]};
            }
        }
        if (doL2) {   // GEMM2: gates2 = A2 @ W2^T  (A2 = [h1(i-1) | h2(i-2)])
            f32x4 a0[2], a1[2];
            #pragma unroll
            for (int nt = 0; nt < 2; ++nt) {
                a0[nt] = (f32x4){bs2[nt], bs2[nt], bs2[nt], bs2[nt]};
                a1[nt] = (f32x4){0.f, 0.f, 0.f, 0.f};
            }
            #pragma unroll
            for (int kt = 0; kt < 4; ++kt) {
                half8 ah = *(const half8*)&A2[aoff + kt * 32];
                half8 al = *(const half8*)&A2[16 * PADH + aoff + kt * 32];
                #pragma unroll
                for (int nt = 0; nt < 2; ++nt) {
                    a0[nt] = __builtin_amdgcn_mfma_f32_16x16x32_f16(ah, w2hi[kt][nt], a0[nt], 0, 0, 0);
                    a1[nt] = __builtin_amdgcn_mfma_f32_16x16x32_f16(ah, w2lo[kt][nt], a1[nt], 0, 0, 0);
                    a1[nt] = __builtin_amdgcn_mfma_f32_16x16x32_f16(al, w2hi[kt][nt], a1[nt], 0, 0, 0);
                }
            }
            #pragma unroll
            for (int nt = 0; nt < 2; ++nt) {
                f32x4 g = a0[nt] + a1[nt] * IC_;
                const int col = w * 32 + nt * 16 + lrow;
                *(f32x2*)&gb2[col * PADR + lkg * 4]     = (f32x2){g[0], g[1]};
                *(f32x2*)&gb2[col * PADR + lkg * 4 + 2] = (f32x2){g[2], g[3]};
            }
        }
        __syncthreads();   // gb ready; A reads drained

        if (doL1) {   // cell1: h1(i) -> A1 h-part AND A2 x-part
            f32x2 gi = *(const f32x2*)&gb1[(0 * 64 + ju) * PADR + ru];
            f32x2 gf = *(const f32x2*)&gb1[(1 * 64 + ju) * PADR + ru];
            f32x2 gg = *(const f32x2*)&gb1[(2 * 64 + ju) * PADR + ru];
            f32x2 go = *(const f32x2*)&gb1[(3 * 64 + ju) * PADR + ru];
            #pragma unroll
            for (int r = 0; r < 2; ++r) {
                c1[r] = fsig(gf[r]) * c1[r] + fsig(gi[r]) * ftanh(gg[r]);
                float hv = fsig(go[r]) * ftanh(c1[r]);
                h1l[r] = hv;
                _Float16 hh = (_Float16)hv;
                _Float16 hl = (_Float16)((hv - (float)hh) * 2048.f);
                A1[(ru + r) * PADH + 64 + ju] = hh;
                A1[16 * PADH + (ru + r) * PADH + 64 + ju] = hl;
                A2[(ru + r) * PADH + ju] = hh;
                A2[16 * PADH + (ru + r) * PADH + ju] = hl;
            }
            if (i + 1 < S) {   // stage x(i+1)
                half2v hi2, lo2;
                hi2[0] = (_Float16)xn[0]; lo2[0] = (_Float16)((xn[0] - (float)hi2[0]) * 2048.f);
                hi2[1] = (_Float16)xn[1]; lo2[1] = (_Float16)((xn[1] - (float)hi2[1]) * 2048.f);
                *(half2v*)&A1[rx * PADH + kx] = hi2;
                *(half2v*)&A1[16 * PADH + rx * PADH + kx] = lo2;
            }
        }
        if (doL2) {   // cell2: h2(i-1) -> A2 h-part + outseq2
            f32x2 gi = *(const f32x2*)&gb2[(0 * 64 + ju) * PADR + ru];
            f32x2 gf = *(const f32x2*)&gb2[(1 * 64 + ju) * PADR + ru];
            f32x2 gg = *(const f32x2*)&gb2[(2 * 64 + ju) * PADR + ru];
            f32x2 go = *(const f32x2*)&gb2[(3 * 64 + ju) * PADR + ru];
            #pragma unroll
            for (int r = 0; r < 2; ++r) {
                c2[r] = fsig(gf[r]) * c2[r] + fsig(gi[r]) * ftanh(gg[r]);
                float hv = fsig(go[r]) * ftanh(c2[r]);
                h2l[r] = hv;
                _Float16 hh = (_Float16)hv;
                A2[(ru + r) * PADH + 64 + ju] = hh;
                A2[16 * PADH + (ru + r) * PADH + 64 + ju] =
                    (_Float16)((hv - (float)hh) * 2048.f);
                outseq2[((size_t)(row0 + ru + r) * S + (i - 1)) * 64 + ju] = hv;
            }
        }
    }
    if (hf1) {
        #pragma unroll
        for (int r = 0; r < 2; ++r) {
            hf1[(size_t)(row0 + ru + r) * 64 + ju] = h1l[r];
            cf1[(size_t)(row0 + ru + r) * 64 + ju] = c1[r];
            hf2[(size_t)(row0 + ru + r) * 64 + ju] = h2l[r];
            cf2[(size_t)(row0 + ru + r) * 64 + ju] = c2[r];
        }
    }
}

// ---------------------------------------------------------------------------
// Helper: stage a fp32 row-block into hi/lo fp16 LDS planes [R][72] (attn0)
// ---------------------------------------------------------------------------
__device__ __forceinline__ void stage_split(const float* __restrict__ src,
                                            _Float16* dst, int plane,
                                            int row, int c0) {
    #pragma unroll
    for (int u = 0; u < 4; ++u) {
        float4 v = *(const float4*)(src + u * 4);
        half4 hi, lo;
        hi[0] = (_Float16)v.x; lo[0] = (_Float16)((v.x - (float)hi[0]) * 2048.f);
        hi[1] = (_Float16)v.y; lo[1] = (_Float16)((v.y - (float)hi[1]) * 2048.f);
        hi[2] = (_Float16)v.z; lo[2] = (_Float16)((v.z - (float)hi[2]) * 2048.f);
        hi[3] = (_Float16)v.w; lo[3] = (_Float16)((v.w - (float)hi[3]) * 2048.f);
        *(half4*)&dst[row * 72 + c0 + u * 4] = hi;
        *(half4*)&dst[plane + row * 72 + c0 + u * 4] = lo;
    }
}

// ---------------------------------------------------------------------------
// Self-attention, last query only (round-3 known-good).
// ---------------------------------------------------------------------------
__global__ __launch_bounds__(256) void attn0_mfma(
    const float* __restrict__ encout,
    const _Float16* __restrict__ wqkvh,
    const float* __restrict__ bqkv,
    const float* __restrict__ Wqkv,
    const float* __restrict__ Wo,
    const float* __restrict__ bo,
    float* __restrict__ a0last)
{
    __shared__ __align__(16) _Float16 E16[2 * 4608];
    __shared__ __align__(16) _Float16 K16[2 * 4608];
    __shared__ __align__(16) _Float16 V16[4608];
    __shared__ float qv[64];
    __shared__ float wrow[4 * 68];
    __shared__ float ov[64];

    const int b = blockIdx.x, tid = threadIdx.x;
    const int w = tid >> 6, l = tid & 63, lr = l & 15, lkg = l >> 4;

    {
        int row = tid >> 2, c0 = (tid & 3) * 16;
        stage_split(encout + (size_t)b * 4096 + row * 64 + c0, E16, 4608, row, c0);
    }
    __syncthreads();

    for (int tt = w; tt < 8; tt += 4) {
        const int kind = (tt < 4) ? 0 : 1;
        const int mrow = (kind ? tt - 4 : tt) * 16;
        const int wrowB = kind ? 128 : 64;
        half8 ah[2], al[2];
        #pragma unroll
        for (int kt = 0; kt < 2; ++kt) {
            int ao = (mrow + lr) * 72 + kt * 32 + lkg * 8;
            ah[kt] = *(const half8*)&E16[ao];
            al[kt] = *(const half8*)&E16[4608 + ao];
        }
        #pragma unroll
        for (int nt = 0; nt < 4; ++nt) {
            const int col = nt * 16 + lr;
            const float bv = bqkv[wrowB + col];
            f32x4 a0 = (f32x4){bv, bv, bv, bv};
            f32x4 a1 = (f32x4){0.f, 0.f, 0.f, 0.f};
            #pragma unroll
            for (int kt = 0; kt < 2; ++kt) {
                const _Float16* wp = wqkvh + (size_t)(wrowB + col) * 64 + kt * 32 + lkg * 8;
                half8 bh = *(const half8*)wp;
                half8 bl = *(const half8*)(wp + 12288);
                a0 = __builtin_amdgcn_mfma_f32_16x16x32_f16(ah[kt], bh, a0, 0, 0, 0);
                a1 = __builtin_amdgcn_mfma_f32_16x16x32_f16(ah[kt], bl, a1, 0, 0, 0);
                a1 = __builtin_amdgcn_mfma_f32_16x16x32_f16(al[kt], bh, a1, 0, 0, 0);
            }
            #pragma unroll
            for (int i = 0; i < 4; ++i) {
                float g = a0[i] + a1[i] * IC_;
                int r = mrow + lkg * 4 + i;
                if (kind == 0) {
                    _Float16 gh = (_Float16)g;
                    K16[r * 72 + col] = gh;
                    K16[4608 + r * 72 + col] = (_Float16)((g - (float)gh) * 2048.f);
                } else {
                    V16[r * 72 + col] = (_Float16)g;
                }
            }
        }
    }
    if (w == 3) {
        float a = bqkv[l];
        for (int k = 0; k < 64; ++k) {
            float e = (float)E16[63 * 72 + k] + (float)E16[4608 + 63 * 72 + k] * IC_;
            a += e * Wqkv[l * 64 + k];
        }
        qv[l] = a;
    }
    __syncthreads();

    {
        const int h = tid >> 6, kv = tid & 63;
        float s = 0.f;
        #pragma unroll
        for (int d = 0; d < 16; ++d) {
            float kk = (float)K16[kv * 72 + h * 16 + d]
                     + (float)K16[4608 + kv * 72 + h * 16 + d] * IC_;
            s += qv[h * 16 + d] * kk;
        }
        s *= 0.25f;
        float m = s;
        #pragma unroll
        for (int off = 32; off; off >>= 1) m = fmaxf(m, __shfl_xor(m, off));
        float e = __expf(s - m);
        float sum = e;
        #pragma unroll
        for (int off = 32; off; off >>= 1) sum += __shfl_xor(sum, off);
        wrow[h * 68 + kv] = e / sum;
    }
    __syncthreads();
    if (tid < 64) {
        const int h = tid >> 4, d = tid & 15;
        float o = 0.f;
        for (int kv = 0; kv < 64; ++kv)
            o += wrow[h * 68 + kv] * (float)V16[kv * 72 + h * 16 + d];
        ov[tid] = o;
    }
    __syncthreads();
    if (tid < 64) {
        float a = bo[tid];
        for (int k = 0; k < 64; ++k) a += ov[k] * Wo[tid * 64 + k];
        a0last[(size_t)b * 64 + tid] = a;
    }
}

// ---------------------------------------------------------------------------
// Cross-attention v2 (round-4 known-good): one b per block, S^T scores,
// no atomics, 4 barriers, 40960 B dynamic LDS.
// ---------------------------------------------------------------------------
__global__ __launch_bounds__(256, 4) void cross_attn_v2(
    const float* __restrict__ encout, const float* __restrict__ decout,
    const _Float16* __restrict__ wqkvh, const float* __restrict__ bqkv,
    _Float16* __restrict__ AOg, float* __restrict__ attnw)
{
    extern __shared__ __align__(16) char smem[];
    _Float16* E  = (_Float16*)(smem);
    _Float16* D  = (_Float16*)(smem + 9216);
    _Float16* K  = (_Float16*)(smem + 16128);
    _Float16* Q  = (_Float16*)(smem + 25344);
    _Float16* VT = (_Float16*)(smem + 32256);

    const int b = blockIdx.x, tid = threadIdx.x;
    const int w = tid >> 6, l = tid & 63, lr = l & 15, lkg = l >> 4;
    const int h = w;

    {
        int row = tid >> 2, c0 = (tid & 3) * 16;
        const float* ep = encout + (size_t)b * 4096 + row * 64 + c0;
        half8 v0, v1;
        #pragma unroll
        for (int j = 0; j < 8; ++j) v0[j] = (_Float16)ep[j];
        #pragma unroll
        for (int j = 0; j < 8; ++j) v1[j] = (_Float16)ep[8 + j];
        *(half8*)&E[row * 72 + c0] = v0;
        *(half8*)&E[row * 72 + c0 + 8] = v1;
        if (row < 48) {
            const float* dp = decout + (size_t)b * 3072 + row * 64 + c0;
            half8 u0, u1;
            #pragma unroll
            for (int j = 0; j < 8; ++j) u0[j] = (_Float16)dp[j];
            #pragma unroll
            for (int j = 0; j < 8; ++j) u1[j] = (_Float16)dp[8 + j];
            *(half8*)&D[row * 72 + c0] = u0;
            *(half8*)&D[row * 72 + c0 + 8] = u1;
        }
    }
    __syncthreads();

    for (int tt = w; tt < 11; tt += 4) {
        const int kind = (tt < 4) ? 0 : ((tt < 8) ? 1 : 2);
        const int mrow = ((kind == 0) ? tt : (kind == 1) ? tt - 4 : tt - 8) * 16;
        const int wrowB = (kind == 0) ? 64 : ((kind == 1) ? 128 : 0);
        const _Float16* S = (kind == 2) ? D : E;
        half8 ah[2];
        #pragma unroll
        for (int kt = 0; kt < 2; ++kt)
            ah[kt] = *(const half8*)&S[(mrow + lr) * 72 + kt * 32 + lkg * 8];
        #pragma unroll
        for (int nt = 0; nt < 4; ++nt) {
            const int col = nt * 16 + lr;
            const float bv = bqkv[wrowB + col];
            f32x4 a0 = (f32x4){bv, bv, bv, bv};
            #pragma unroll
            for (int kt = 0; kt < 2; ++kt) {
                half8 bh = *(const half8*)&wqkvh[(size_t)(wrowB + col) * 64 + kt * 32 + lkg * 8];
                a0 = __builtin_amdgcn_mfma_f32_16x16x32_f16(ah[kt], bh, a0, 0, 0, 0);
            }
            if (kind == 1) {
                half4 p;
                #pragma unroll
                for (int i = 0; i < 4; ++i) p[i] = (_Float16)a0[i];
                *(half4*)&VT[col * 68 + mrow + lkg * 4] = p;
            } else {
                _Float16* dst = (kind == 0) ? K : Q;
                #pragma unroll
                for (int i = 0; i < 4; ++i)
                    dst[(mrow + lkg * 4 + i) * 72 + col] = (_Float16)a0[i];
            }
        }
    }
    __syncthreads();

    const half8 z = {0, 0, 0, 0, 0, 0, 0, 0};
    half8 ka[4], qb[3];
    #pragma unroll
    for (int kvt = 0; kvt < 4; ++kvt)
        ka[kvt] = (lkg < 2) ? *(const half8*)&K[(kvt * 16 + lr) * 72 + h * 16 + lkg * 8] : z;
    #pragma unroll
    for (int qt = 0; qt < 3; ++qt)
        qb[qt] = (lkg < 2) ? *(const half8*)&Q[(qt * 16 + lr) * 72 + h * 16 + lkg * 8] : z;
    __syncthreads();

    _Float16* strip = (_Float16*)(smem + ((h == 0) ? 0 : (h == 1) ? 9216
                                        : (h == 2) ? 16128 : 25344));
    {
        f32x4 s[3][4];
        #pragma unroll
        for (int qt = 0; qt < 3; ++qt) {
            #pragma unroll
            for (int kvt = 0; kvt < 4; ++kvt) {
                f32x4 a0 = (f32x4){0.f, 0.f, 0.f, 0.f};
                a0 = __builtin_amdgcn_mfma_f32_16x16x32_f16(ka[kvt], qb[qt], a0, 0, 0, 0);
                s[qt][kvt] = a0 * 0.25f;
            }
            float m = s[qt][0][0];
            #pragma unroll
            for (int kvt = 0; kvt < 4; ++kvt)
                #pragma unroll
                for (int i = 0; i < 4; ++i) m = fmaxf(m, s[qt][kvt][i]);
            m = fmaxf(m, __shfl_xor(m, 16));
            m = fmaxf(m, __shfl_xor(m, 32));
            float sum = 0.f;
            #pragma unroll
            for (int kvt = 0; kvt < 4; ++kvt)
                #pragma unroll
                for (int i = 0; i < 4; ++i) {
                    float e = __expf(s[qt][kvt][i] - m);
                    s[qt][kvt][i] = e;
                    sum += e;
                }
            sum += __shfl_xor(sum, 16);
            sum += __shfl_xor(sum, 32);
            const float r = 1.0f / sum;
            #pragma unroll
            for (int kvt = 0; kvt < 4; ++kvt) {
                half4 p;
                #pragma unroll
                for (int i = 0; i < 4; ++i) p[i] = (_Float16)(s[qt][kvt][i] * r);
                *(half4*)&strip[(qt * 16 + lr) * 72 + kvt * 16 + lkg * 4] = p;
            }
        }
    }
    {
        half8 vb[2];
        #pragma unroll
        for (int kt = 0; kt < 2; ++kt) {
            half4 lo4 = *(const half4*)&VT[(h * 16 + lr) * 68 + kt * 32 + lkg * 8];
            half4 hi4 = *(const half4*)&VT[(h * 16 + lr) * 68 + kt * 32 + lkg * 8 + 4];
            #pragma unroll
            for (int j = 0; j < 4; ++j) { vb[kt][j] = lo4[j]; vb[kt][4 + j] = hi4[j]; }
        }
        #pragma unroll
        for (int qt = 0; qt < 3; ++qt) {
            f32x4 acc = (f32x4){0.f, 0.f, 0.f, 0.f};
            #pragma unroll
            for (int kt = 0; kt < 2; ++kt) {
                half8 wa = *(const half8*)&strip[(qt * 16 + lr) * 72 + kt * 32 + lkg * 8];
                acc = __builtin_amdgcn_mfma_f32_16x16x32_f16(wa, vb[kt], acc, 0, 0, 0);
            }
            #pragma unroll
            for (int i = 0; i < 4; ++i)
                AOg[((size_t)b * 48 + qt * 16 + lkg * 4 + i) * 64 + h * 16 + lr] =
                    (_Float16)acc[i];
        }
    }
    __syncthreads();

    {
        const _Float16* s0 = (const _Float16*)(smem);
        const _Float16* s1 = (const _Float16*)(smem + 9216);
        const _Float16* s2 = (const _Float16*)(smem + 16128);
        const _Float16* s3 = (const _Float16*)(smem + 25344);
        #pragma unroll
        for (int it = 0; it < 12; ++it) {
            int idx = tid + it * 256;
            int o = (idx >> 6) * 72 + (idx & 63);
            attnw[(size_t)b * 3072 + idx] =
                0.25f * ((float)s0[o] + (float)s1[o] + (float)s2[o] + (float)s3[o]);
        }
    }
}

// ---------------------------------------------------------------------------
// Batched out-proj + FC1(relu) + FC2. 64 rows/block, zero barriers.
// ---------------------------------------------------------------------------
__global__ __launch_bounds__(256) void proj_fc_kernel(
    const _Float16* __restrict__ AOg,
    const _Float16* __restrict__ woh, const float* __restrict__ bo,
    const _Float16* __restrict__ w1h, const float* __restrict__ b1,
    const float* __restrict__ W2,     const float* __restrict__ b2,
    float* __restrict__ pred)
{
    __shared__ __align__(16) _Float16 obuf[4][16 * 72];
    __shared__ float h1buf[4][16 * 36];
    const int tid = threadIdx.x;
    const int w = tid >> 6, l = tid & 63, lr = l & 15, lkg = l >> 4;
    const size_t r0 = (size_t)blockIdx.x * 64 + w * 16;

    half8 ah[2];
    #pragma unroll
    for (int kt = 0; kt < 2; ++kt)
        ah[kt] = *(const half8*)&AOg[(r0 + lr) * 64 + kt * 32 + lkg * 8];
    #pragma unroll
    for (int nt = 0; nt < 4; ++nt) {
        const int col = nt * 16 + lr;
        const float bv = bo[col];
        f32x4 a0 = (f32x4){bv, bv, bv, bv};
        #pragma unroll
        for (int kt = 0; kt < 2; ++kt) {
            half8 bh = *(const half8*)&woh[(size_t)col * 64 + kt * 32 + lkg * 8];
            a0 = __builtin_amdgcn_mfma_f32_16x16x32_f16(ah[kt], bh, a0, 0, 0, 0);
        }
        #pragma unroll
        for (int i = 0; i < 4; ++i)
            obuf[w][(lkg * 4 + i) * 72 + col] = (_Float16)a0[i];
    }
    half8 oh[2];
    #pragma unroll
    for (int kt = 0; kt < 2; ++kt)
        oh[kt] = *(const half8*)&obuf[w][lr * 72 + kt * 32 + lkg * 8];
    #pragma unroll
    for (int nt = 0; nt < 2; ++nt) {
        const int m = nt * 16 + lr;
        const float bv = b1[m];
        f32x4 a0 = (f32x4){bv, bv, bv, bv};
        #pragma unroll
        for (int kt = 0; kt < 2; ++kt) {
            half8 bh = *(const half8*)&w1h[(size_t)m * 64 + kt * 32 + lkg * 8];
            a0 = __builtin_amdgcn_mfma_f32_16x16x32_f16(oh[kt], bh, a0, 0, 0, 0);
        }
        #pragma unroll
        for (int i = 0; i < 4; ++i)
            h1buf[w][(lkg * 4 + i) * 36 + m] = fmaxf(a0[i], 0.f);
    }
    if (l < 48) {
        const int q = l / 3, n = l - 3 * q;
        float a = b2[n];
        #pragma unroll
        for (int m2 = 0; m2 < 32; ++m2)
            a += h1buf[w][q * 36 + m2] * W2[n * 32 + m2];
        pred[(r0 + q) * 3 + n] = a;
    }
}

// ---------------------------------------------------------------------------
extern "C" void kernel_launch(void* const* d_in, const int* in_sizes, int n_in,
                              void* d_out, int out_size, void* d_ws, size_t ws_size,
                              hipStream_t stream) {
    const float* x      = (const float*)d_in[0];
    const float* target = (const float*)d_in[1];
    const float* eWih0 = (const float*)d_in[2],  *eWhh0 = (const float*)d_in[3];
    const float* ebih0 = (const float*)d_in[4],  *ebhh0 = (const float*)d_in[5];
    const float* eWih1 = (const float*)d_in[6],  *eWhh1 = (const float*)d_in[7];
    const float* ebih1 = (const float*)d_in[8],  *ebhh1 = (const float*)d_in[9];
    const float* dWih0 = (const float*)d_in[10], *dWhh0 = (const float*)d_in[11];
    const float* dbih0 = (const float*)d_in[12], *dbhh0 = (const float*)d_in[13];
    const float* dWih1 = (const float*)d_in[14], *dWhh1 = (const float*)d_in[15];
    const float* dbih1 = (const float*)d_in[16], *dbhh1 = (const float*)d_in[17];
    const float* Wqkv = (const float*)d_in[18], *bqkv = (const float*)d_in[19];
    const float* Wo   = (const float*)d_in[20], *bo   = (const float*)d_in[21];
    const float* W1   = (const float*)d_in[22], *b1   = (const float*)d_in[23];
    const float* W2   = (const float*)d_in[24], *b2   = (const float*)d_in[25];

    float* ws = (float*)d_ws;
    float* hseq1  = ws;                                   // AOg alias region
    float* encout = hseq1  + (size_t)B_ * L_ * H_;
    float* decout = encout + (size_t)B_ * L_ * H_;
    float* a0last = decout + (size_t)B_ * T_ * H_;
    float* hfin   = a0last + (size_t)B_ * H_;
    float* cfin   = hfin   + (size_t)2 * B_ * H_;
    float* wtg    = cfin   + (size_t)2 * B_ * H_;
    float* auxw   = wtg    + (size_t)4 * 32768;

    _Float16* wh0 = (_Float16*)(wtg);
    _Float16* wh1 = wh0 + 65536;
    _Float16* wh2 = wh1 + 65536;
    _Float16* wh3 = wh2 + 65536;
    _Float16* wqkvh = (_Float16*)auxw;        // [2][192][64]
    _Float16* woh   = wqkvh + 24576;          // [2][64][64]
    _Float16* w1h   = woh + 8192;             // [2][32][64]
    _Float16* AOg   = (_Float16*)hseq1;

    float* pred  = (float*)d_out;
    float* attnw = pred + (size_t)B_ * T_ * 3;

    transpose_w_kernel<<<64, 256, 0, stream>>>(eWih0, eWhh0, wh0);
    transpose_w_kernel<<<64, 256, 0, stream>>>(eWih1, eWhh1, wh1);
    transpose_w_kernel<<<64, 256, 0, stream>>>(dWih0, dWhh0, wh2);
    transpose_w_kernel<<<64, 256, 0, stream>>>(dWih1, dWhh1, wh3);
    split_aux_kernel<<<72, 256, 0, stream>>>(Wqkv, Wo, W1, wqkvh, woh, w1h);

    // fused encoder (both layers, skewed)
    lstm2_mfma_kernel<<<256, 512, 0, stream>>>(
        x, nullptr, wh0, ebih0, ebhh0, wh1, ebih1, ebhh1,
        nullptr, nullptr, nullptr, nullptr,
        encout, hfin, cfin, hfin + (size_t)B_ * H_, cfin + (size_t)B_ * H_, L_, 0);
    // self-attn, last query
    attn0_mfma<<<B_, 256, 0, stream>>>(encout, wqkvh, bqkv, Wqkv, Wo, bo, a0last);
    // fused decoder
    lstm2_mfma_kernel<<<256, 512, 0, stream>>>(
        target, a0last, wh2, dbih0, dbhh0, wh3, dbih1, dbhh1,
        hfin, cfin, hfin + (size_t)B_ * H_, cfin + (size_t)B_ * H_,
        decout, nullptr, nullptr, nullptr, nullptr, T_, 1);
    // cross-attention -> AOg, attnw
    cross_attn_v2<<<B_, 256, 40960, stream>>>(
        encout, decout, wqkvh, bqkv, AOg, attnw);
    // out-proj + FC1 + FC2 -> pred
    proj_fc_kernel<<<(B_ * T_) / 64, 256, 0, stream>>>(
        AOg, woh, bo, w1h, b1, W2, b2, pred);
}